// Round 4
// baseline (351.887 us; speedup 1.0000x reference)
//
#include <hip/hip_runtime.h>
#include <math.h>

#define NN   50000
#define NE   1600000
#define FIN  512
#define H1F  128
#define NCHUNK 49    // ceil(NN/1024)
#define NBUK  391    // ceil(NN/128)  — dst-bucket = 128 consecutive nodes

typedef __attribute__((ext_vector_type(8))) short bf16x8;
typedef __attribute__((ext_vector_type(4))) float f32x4;

// ---------------- bf16 helpers ----------------
__device__ __forceinline__ float bflo(unsigned v) { return __uint_as_float(v << 16); }
__device__ __forceinline__ float bfhi(unsigned v) { return __uint_as_float(v & 0xffff0000u); }
__device__ __forceinline__ unsigned short f2bf(float f) {
  unsigned u = __float_as_uint(f);
  u += 0x7fffu + ((u >> 16) & 1u);   // round-to-nearest-even
  return (unsigned short)(u >> 16);
}
__device__ __forceinline__ unsigned pack2bf(float a, float b) {
  return (unsigned)f2bf(a) | ((unsigned)f2bf(b) << 16);
}

// ---------------- setup kernels (degree / scan / CSR fill) ----------------

__global__ __launch_bounds__(256) void k_init(int* __restrict__ deg, int* __restrict__ bcur) {
  int i = blockIdx.x * 256 + threadIdx.x;
  if (i < NN) deg[i] = 0;
  if (i < NBUK * 16) bcur[i] = 0;
}

__global__ __launch_bounds__(256) void k_count(const int* __restrict__ ei, int* __restrict__ deg) {
  int e = blockIdx.x * 256 + threadIdx.x;
  if (e < NE) atomicAdd(&deg[ei[NE + e]], 1);
}

__global__ __launch_bounds__(256) void k_partial(const int* __restrict__ deg,
                                                 int* __restrict__ csums,
                                                 float* __restrict__ dinv) {
  __shared__ int red[256];
  int t = threadIdx.x;
  int base = blockIdx.x * 1024 + t * 4;
  int s = 0;
#pragma unroll
  for (int j = 0; j < 4; ++j) {
    int i = base + j;
    if (i < NN) {
      int d = deg[i];
      s += d;
      dinv[i] = rsqrtf((float)(d + 1));   // self-loop included; deg_hat >= 1
    }
  }
  red[t] = s;
  __syncthreads();
  for (int off = 128; off > 0; off >>= 1) {
    if (t < off) red[t] += red[t + off];
    __syncthreads();
  }
  if (t == 0) csums[blockIdx.x] = red[0];
}

__global__ void k_top(int* __restrict__ csums, int* __restrict__ rowptr) {
  if (threadIdx.x == 0 && blockIdx.x == 0) {
    int run = 0;
    for (int c = 0; c < NCHUNK; ++c) { int v = csums[c]; csums[c] = run; run += v; }
    rowptr[NN] = run;   // == NE
  }
}

__global__ __launch_bounds__(256) void k_scan(const int* __restrict__ deg,
                                              const int* __restrict__ csums,
                                              int* __restrict__ rowptr) {
  __shared__ int ts[256];
  int t = threadIdx.x;
  int base = blockIdx.x * 1024 + t * 4;
  int v[4];
  int s = 0;
#pragma unroll
  for (int j = 0; j < 4; ++j) {
    v[j] = (base + j < NN) ? deg[base + j] : 0;
    s += v[j];
  }
  ts[t] = s;
  __syncthreads();
  for (int off = 1; off < 256; off <<= 1) {
    int val = ts[t];
    int add = (t >= off) ? ts[t - off] : 0;
    __syncthreads();
    ts[t] = val + add;
    __syncthreads();
  }
  int excl = (t ? ts[t - 1] : 0) + csums[blockIdx.x];
#pragma unroll
  for (int j = 0; j < 4; ++j) {
    if (base + j < NN) rowptr[base + j] = excl;
    excl += v[j];
  }
}

// Phase 1: scatter edges into dst-bucket runs (bucket = dst>>7).
// bbase[b] == rowptr[b<<7] (dst-contiguous buckets) -> no extra scan needed.
// bcur padded to 64B/counter so each counter owns its own cache line.
__global__ __launch_bounds__(256) void k_fill1(const int* __restrict__ ei,
                                               const int* __restrict__ rowptr,
                                               int* __restrict__ bcur,
                                               unsigned* __restrict__ tmp) {
  int e = blockIdx.x * 256 + threadIdx.x;
  if (e >= NE) return;
  int s = ei[e];
  int d = ei[NE + e];
  int b = d >> 7;
  int p = atomicAdd(&bcur[b * 16], 1);
  tmp[rowptr[b << 7] + p] = ((unsigned)s << 16) | (unsigned)d;
}

// Phase 2: one block per bucket; LDS per-dst cursors; csr writes land in the
// bucket's ~16KB window (L2-resident, no write-allocate amplification).
__global__ __launch_bounds__(256) void k_fill2(const unsigned* __restrict__ tmp,
                                               const int* __restrict__ rowptr,
                                               int* __restrict__ csr) {
  __shared__ int cur[128];
  int b  = blockIdx.x;
  int t  = threadIdx.x;
  int n0 = b << 7;
  int n1 = n0 + 128; if (n1 > NN) n1 = NN;
  if (t < 128) cur[t] = 0;
  int beg = rowptr[n0];
  int end = rowptr[n1];
  __syncthreads();
  for (int i = beg + t; i < end; i += 256) {
    unsigned pk = tmp[i];
    int d = (int)(pk & 0xFFFFu);
    int s = (int)(pk >> 16);
    int p = atomicAdd(&cur[d - n0], 1);
    csr[rowptr[d] + p] = s;
  }
}

// ---------------- W1 -> W1^T bf16  ([512][128] f32 -> [128][512] bf16) ----------------

__global__ __launch_bounds__(256) void k_cvtw1(const float* __restrict__ W,
                                               unsigned short* __restrict__ Wt) {
  int i = blockIdx.x * 256 + threadIdx.x;
  if (i < FIN * H1F) {
    int k = i >> 7, c = i & 127;          // coalesced read of W[k][c]
    Wt[c * FIN + k] = f2bf(W[i]);
  }
}

// ---------------- GEMM1 (MFMA): hw1 = bf16(x @ W1) ----------------
// BM=64 rows x 128 cols per block, 4 waves (wave = 16 rows x 128 cols).
// K staged in 16 steps of 32. A converted f32->bf16 in-register.
// LDS rows padded to 80B (5-word stride) for conflict-free ds_read_b128.
// mfma(Wt_frag, x_frag): lane holds C[row=lane&15][col=f*16+(lane>>4)*4 + 0..3].

#define G1_ABUF 5120          // 64 rows * 80B
#define G1_BBUF 10240         // 128 cols * 80B
#define G1_BUF  (G1_ABUF + G1_BBUF)
#define G1_NSTEP 16

__global__ __launch_bounds__(256) void k_gemm1m(const float* __restrict__ X,
                                                const unsigned short* __restrict__ W1t,
                                                unsigned short* __restrict__ outb) {
  __shared__ char lds[2 * G1_BUF];
  int tid  = threadIdx.x;
  int row0 = blockIdx.x * 64;
  int w    = tid >> 6;
  int lane = tid & 63;

  // staging roles
  int ar = tid >> 2, aq = tid & 3;        // A: row ar, k-chunk aq (8 floats)
  int bc = tid >> 1, bh = tid & 1;        // B: col bc, half bh (16 bf16)

  float4 av0, av1;
  uint4  bu0, bu1;

  auto load_g = [&](int s) {
    int k0 = s * 32;
    int row = row0 + ar;
    av0 = make_float4(0.f, 0.f, 0.f, 0.f);
    av1 = av0;
    if (row < NN) {
      const float* gp = X + (size_t)row * FIN + k0 + aq * 8;
      av0 = *(const float4*)gp;
      av1 = *(const float4*)(gp + 4);
    }
    const uint4* bp = (const uint4*)(W1t + (size_t)bc * FIN + k0 + bh * 16);
    bu0 = bp[0];
    bu1 = bp[1];
  };
  auto store_l = [&](int buf) {
    char* Ab = lds + buf * G1_BUF;
    char* Bb = Ab + G1_ABUF;
    uint4 ap;
    ap.x = pack2bf(av0.x, av0.y); ap.y = pack2bf(av0.z, av0.w);
    ap.z = pack2bf(av1.x, av1.y); ap.w = pack2bf(av1.z, av1.w);
    *(uint4*)(Ab + ar * 80 + aq * 16) = ap;
    *(uint4*)(Bb + bc * 80 + bh * 32)      = bu0;
    *(uint4*)(Bb + bc * 80 + bh * 32 + 16) = bu1;
  };

  f32x4 acc[8];
#pragma unroll
  for (int f = 0; f < 8; ++f) acc[f] = (f32x4){0.f, 0.f, 0.f, 0.f};

  load_g(0);
  store_l(0);

  for (int s = 0; s < G1_NSTEP; ++s) {
    if (s + 1 < G1_NSTEP) load_g(s + 1);      // overlap HBM latency with MFMA
    __syncthreads();                           // buf[s&1] writes complete
    const char* Ab = lds + (s & 1) * G1_BUF;
    const char* Bb = Ab + G1_ABUF;
    bf16x8 xa = *(const bf16x8*)(Ab + (w * 16 + (lane & 15)) * 80 + (lane >> 4) * 16);
#pragma unroll
    for (int f = 0; f < 8; ++f) {
      bf16x8 bt = *(const bf16x8*)(Bb + (f * 16 + (lane & 15)) * 80 + (lane >> 4) * 16);
      acc[f] = __builtin_amdgcn_mfma_f32_16x16x32_bf16(bt, xa, acc[f], 0, 0, 0);
    }
    if (s + 1 < G1_NSTEP) store_l((s + 1) & 1);  // write-late into other buffer
  }

  int orow = row0 + w * 16 + (lane & 15);
  if (orow < NN) {
    size_t base = (size_t)orow * H1F;
#pragma unroll
    for (int f = 0; f < 8; ++f) {
      int col = f * 16 + (lane >> 4) * 4;
      uint2 pk;
      pk.x = pack2bf(acc[f][0], acc[f][1]);
      pk.y = pack2bf(acc[f][2], acc[f][3]);
      *(uint2*)(outb + base + col) = pk;       // 8B store, 8B-aligned
    }
  }
}

// ---------------- aggregation over bf16 feature table ----------------
// out[d] = dinv[d]*(sum_{s in N(d)} dinv[s]*feat[s] + dinv[d]*feat[d]) (+bias)
// one wave per dst node; 2 feats/lane packed in one uint (256B gather per edge).

template<bool BIAS, bool OUTBF>
__global__ __launch_bounds__(256) void k_aggb(const unsigned* __restrict__ feat,   // [NN][64] uints
                                              const int* __restrict__ rowptr,
                                              const int* __restrict__ csr,
                                              const float* __restrict__ dinv,
                                              const float* __restrict__ bias,
                                              void* __restrict__ out) {
  int gw   = (blockIdx.x * 256 + threadIdx.x) >> 6;   // dst node
  int lane = threadIdx.x & 63;
  if (gw >= NN) return;
  int beg = rowptr[gw], end = rowptr[gw + 1];
  float di = dinv[gw];
  float ax = 0.f, ay = 0.f;

  for (int e = beg; e < end; e += 64) {
    int cnt = end - e; if (cnt > 64) cnt = 64;
    int sv = 0; float wv = 0.f;
    if (lane < cnt) { sv = csr[e + lane]; wv = dinv[sv]; }
    int j = 0;
    for (; j + 4 <= cnt; j += 4) {
      int s0 = __shfl(sv, j),     s1 = __shfl(sv, j + 1);
      int s2 = __shfl(sv, j + 2), s3 = __shfl(sv, j + 3);
      float w0 = __shfl(wv, j),     w1 = __shfl(wv, j + 1);
      float w2 = __shfl(wv, j + 2), w3 = __shfl(wv, j + 3);
      unsigned v0 = feat[(size_t)s0 * 64 + lane];
      unsigned v1 = feat[(size_t)s1 * 64 + lane];
      unsigned v2 = feat[(size_t)s2 * 64 + lane];
      unsigned v3 = feat[(size_t)s3 * 64 + lane];
      ax += w0 * bflo(v0); ay += w0 * bfhi(v0);
      ax += w1 * bflo(v1); ay += w1 * bfhi(v1);
      ax += w2 * bflo(v2); ay += w2 * bfhi(v2);
      ax += w3 * bflo(v3); ay += w3 * bfhi(v3);
    }
    for (; j < cnt; ++j) {
      int s = __shfl(sv, j);
      float w = __shfl(wv, j);
      unsigned v = feat[(size_t)s * 64 + lane];
      ax += w * bflo(v); ay += w * bfhi(v);
    }
  }
  // self loop
  unsigned vd = feat[(size_t)gw * 64 + lane];
  ax = di * (ax + di * bflo(vd));
  ay = di * (ay + di * bfhi(vd));
  if (BIAS) { ax += bias[lane * 2]; ay += bias[lane * 2 + 1]; }
  if (OUTBF) {
    ((unsigned*)out)[(size_t)gw * 64 + lane] = pack2bf(ax, ay);
  } else {
    ((float2*)out)[(size_t)gw * 64 + lane] = make_float2(ax, ay);
  }
}

// ---------------- GEMM2 fused: [mu|logvar] = g @ [W2|W3] + [b2|b3]; z = eps*exp(logvar)+mu ----------------

__global__ __launch_bounds__(256) void k_gemm2z(const float* __restrict__ G,
                                                const float* __restrict__ W2,
                                                const float* __restrict__ W3,
                                                const float* __restrict__ b2,
                                                const float* __restrict__ b3,
                                                const float* __restrict__ eps,
                                                float* __restrict__ z) {
  __shared__ float As[64][32];
  __shared__ float Bs[32][128];
  int tid  = threadIdx.x;
  int row0 = blockIdx.x * 64;
  int tcol = tid & 31;
  int trow = (tid >> 5) * 8;
  float acc[8][4] = {};
  for (int k0 = 0; k0 < H1F; k0 += 32) {
#pragma unroll
    for (int i = 0; i < 2; ++i) {
      int f = tid + i * 256;
      int r = f >> 3, kq = (f & 7) * 4;
      float4 v = make_float4(0.f, 0.f, 0.f, 0.f);
      if (row0 + r < NN) v = *(const float4*)&G[(size_t)(row0 + r) * H1F + k0 + kq];
      *(float4*)&As[r][kq] = v;
    }
#pragma unroll
    for (int i = 0; i < 4; ++i) {
      int f = tid + i * 256;
      int r = f >> 5, c = (f & 31) * 4;
      float4 v;
      if (c < 64) v = *(const float4*)&W2[(size_t)(k0 + r) * 64 + c];
      else        v = *(const float4*)&W3[(size_t)(k0 + r) * 64 + (c - 64)];
      *(float4*)&Bs[r][c] = v;
    }
    __syncthreads();
#pragma unroll
    for (int kk = 0; kk < 32; ++kk) {
      float a[8];
#pragma unroll
      for (int r = 0; r < 8; ++r) a[r] = As[trow + r][kk];
      float b0 = Bs[kk][tcol], b1v = Bs[kk][tcol + 32];
      float b2v = Bs[kk][tcol + 64], b3v = Bs[kk][tcol + 96];
#pragma unroll
      for (int r = 0; r < 8; ++r) {
        acc[r][0] += a[r] * b0;  acc[r][1] += a[r] * b1v;
        acc[r][2] += a[r] * b2v; acc[r][3] += a[r] * b3v;
      }
    }
    __syncthreads();
  }
  float bb2a = b2[tcol], bb2b = b2[tcol + 32];
  float bb3a = b3[tcol], bb3b = b3[tcol + 32];
#pragma unroll
  for (int r = 0; r < 8; ++r) {
    int row = row0 + trow + r;
    if (row < NN) {
      float mu0 = acc[r][0] + bb2a;
      float mu1 = acc[r][1] + bb2b;
      float lv0 = acc[r][2] + bb3a;
      float lv1 = acc[r][3] + bb3b;
      size_t base = (size_t)row * 64;
      z[base + tcol]      = eps[base + tcol]      * __expf(lv0) + mu0;
      z[base + tcol + 32] = eps[base + tcol + 32] * __expf(lv1) + mu1;
    }
  }
}

// ---------------- launch ----------------

extern "C" void kernel_launch(void* const* d_in, const int* in_sizes, int n_in,
                              void* d_out, int out_size, void* d_ws, size_t ws_size,
                              hipStream_t stream) {
  const float* x   = (const float*)d_in[0];
  const int*   ei  = (const int*)  d_in[1];
  const float* W1  = (const float*)d_in[2];
  const float* b1  = (const float*)d_in[3];
  const float* W2  = (const float*)d_in[4];
  const float* b2  = (const float*)d_in[5];
  const float* W3  = (const float*)d_in[6];
  const float* b3  = (const float*)d_in[7];
  const float* eps = (const float*)d_in[8];
  float* z = (float*)d_out;

  char* ws = (char*)d_ws;
  size_t o = 0;
  auto alloc = [&](size_t bytes) -> void* {
    void* p = ws + o;
    o = (o + bytes + 255) & ~(size_t)255;
    return p;
  };
  int*   deg    = (int*)  alloc((size_t)NN * 4);
  int*   rowptr = (int*)  alloc((size_t)(NN + 1) * 4);
  int*   bcur   = (int*)  alloc((size_t)NBUK * 16 * 4);   // 64B-padded bucket cursors
  int*   csums  = (int*)  alloc((size_t)NCHUNK * 4);
  float* dinv   = (float*)alloc((size_t)NN * 4);
  int*   csr    = (int*)  alloc((size_t)NE * 4);
  unsigned short* W1t  = (unsigned short*)alloc((size_t)H1F * FIN * 2);  // bf16 W1^T
  unsigned short* hw1b = (unsigned short*)alloc((size_t)NN * H1F * 2);   // bf16 x@W1
  unsigned short* h1b  = (unsigned short*)alloc((size_t)NN * H1F * 2);   // bf16 h1
  float* g = (float*)alloc((size_t)NN * H1F * 4);                        // f32 Agg(h1)
  unsigned* tmp = (unsigned*)g;   // bucketed edges; dead before agg2 writes g

  k_init   <<<(NN + 255) / 256, 256, 0, stream>>>(deg, bcur);
  k_count  <<<(NE + 255) / 256, 256, 0, stream>>>(ei, deg);
  k_partial<<<NCHUNK, 256, 0, stream>>>(deg, csums, dinv);
  k_top    <<<1, 64, 0, stream>>>(csums, rowptr);
  k_scan   <<<NCHUNK, 256, 0, stream>>>(deg, csums, rowptr);
  k_fill1  <<<(NE + 255) / 256, 256, 0, stream>>>(ei, rowptr, bcur, tmp);
  k_fill2  <<<NBUK, 256, 0, stream>>>(tmp, rowptr, csr);
  k_cvtw1  <<<(FIN * H1F + 255) / 256, 256, 0, stream>>>(W1, W1t);

  k_gemm1m <<<(NN + 63) / 64, 256, 0, stream>>>(x, W1t, hw1b);
  k_aggb<true,  true ><<<(NN + 3) / 4, 256, 0, stream>>>((const unsigned*)hw1b, rowptr, csr, dinv, b1, (void*)h1b);
  k_aggb<false, false><<<(NN + 3) / 4, 256, 0, stream>>>((const unsigned*)h1b,  rowptr, csr, dinv, nullptr, (void*)g);
  k_gemm2z <<<(NN + 63) / 64, 256, 0, stream>>>(g, W2, W3, b2, b3, eps, z);
}

// Round 5
// 292.974 us; speedup vs baseline: 1.2011x; 1.2011x over previous
//
#include <hip/hip_runtime.h>
#include <math.h>

#define NN   50000
#define NE   1600000
#define FIN  512
#define H1F  128
#define NCHUNK 49    // ceil(NN/1024)
#define NBUK  391    // ceil(NN/128)  — dst-bucket = 128 consecutive nodes
#define BIN_EPB 4096 // edges per binning block (16 per thread)
#define NBIN  391    // ceil(NE/BIN_EPB)

typedef __attribute__((ext_vector_type(8))) short bf16x8;
typedef __attribute__((ext_vector_type(4))) float f32x4;

// ---------------- bf16 helpers ----------------
__device__ __forceinline__ float bflo(unsigned v) { return __uint_as_float(v << 16); }
__device__ __forceinline__ float bfhi(unsigned v) { return __uint_as_float(v & 0xffff0000u); }
__device__ __forceinline__ unsigned short f2bf(float f) {
  unsigned u = __float_as_uint(f);
  u += 0x7fffu + ((u >> 16) & 1u);   // round-to-nearest-even
  return (unsigned short)(u >> 16);
}
__device__ __forceinline__ unsigned pack2bf(float a, float b) {
  return (unsigned)f2bf(a) | ((unsigned)f2bf(b) << 16);
}

// ---------------- setup kernels (degree / scan / CSR fill) ----------------

__global__ __launch_bounds__(256) void k_init(int* __restrict__ deg, int* __restrict__ bcur) {
  int i = blockIdx.x * 256 + threadIdx.x;
  if (i < NN) deg[i] = 0;
  if (i < NBUK) bcur[i] = 0;
}

__global__ __launch_bounds__(256) void k_count(const int* __restrict__ ei, int* __restrict__ deg) {
  int e = blockIdx.x * 256 + threadIdx.x;
  if (e < NE) atomicAdd(&deg[ei[NE + e]], 1);
}

__global__ __launch_bounds__(256) void k_partial(const int* __restrict__ deg,
                                                 int* __restrict__ csums,
                                                 float* __restrict__ dinv) {
  __shared__ int red[256];
  int t = threadIdx.x;
  int base = blockIdx.x * 1024 + t * 4;
  int s = 0;
#pragma unroll
  for (int j = 0; j < 4; ++j) {
    int i = base + j;
    if (i < NN) {
      int d = deg[i];
      s += d;
      dinv[i] = rsqrtf((float)(d + 1));   // self-loop included; deg_hat >= 1
    }
  }
  red[t] = s;
  __syncthreads();
  for (int off = 128; off > 0; off >>= 1) {
    if (t < off) red[t] += red[t + off];
    __syncthreads();
  }
  if (t == 0) csums[blockIdx.x] = red[0];
}

__global__ void k_top(int* __restrict__ csums, int* __restrict__ rowptr) {
  if (threadIdx.x == 0 && blockIdx.x == 0) {
    int run = 0;
    for (int c = 0; c < NCHUNK; ++c) { int v = csums[c]; csums[c] = run; run += v; }
    rowptr[NN] = run;   // == NE
  }
}

__global__ __launch_bounds__(256) void k_scan(const int* __restrict__ deg,
                                              const int* __restrict__ csums,
                                              int* __restrict__ rowptr) {
  __shared__ int ts[256];
  int t = threadIdx.x;
  int base = blockIdx.x * 1024 + t * 4;
  int v[4];
  int s = 0;
#pragma unroll
  for (int j = 0; j < 4; ++j) {
    v[j] = (base + j < NN) ? deg[base + j] : 0;
    s += v[j];
  }
  ts[t] = s;
  __syncthreads();
  for (int off = 1; off < 256; off <<= 1) {
    int val = ts[t];
    int add = (t >= off) ? ts[t - off] : 0;
    __syncthreads();
    ts[t] = val + add;
    __syncthreads();
  }
  int excl = (t ? ts[t - 1] : 0) + csums[blockIdx.x];
#pragma unroll
  for (int j = 0; j < 4; ++j) {
    if (base + j < NN) rowptr[base + j] = excl;
    excl += v[j];
  }
}

// Binning with block-local histogram + PACKED writes.
// Each block: 4096 edges -> LDS hist over 391 buckets -> one global atomic per
// (block,bucket) reserves a contiguous range -> bucket-grouped edges written
// contiguously (line-efficient, ~2x amplification instead of ~16x).
__global__ __launch_bounds__(256) void k_bin(const int* __restrict__ ei,
                                             const int* __restrict__ rowptr,
                                             int* __restrict__ bcur,
                                             unsigned* __restrict__ tmp) {
  __shared__ int hist[NBUK];
  __shared__ int sbase[NBUK];
  int t  = threadIdx.x;
  int e0 = blockIdx.x * BIN_EPB;
  for (int b = t; b < NBUK; b += 256) hist[b] = 0;
  __syncthreads();

  unsigned short d16[16];
  unsigned short p16[16];
#pragma unroll
  for (int j = 0; j < 16; ++j) {
    int e = e0 + j * 256 + t;
    d16[j] = 0xFFFFu;
    if (e < NE) {
      int d = ei[NE + e];
      d16[j] = (unsigned short)d;
      p16[j] = (unsigned short)atomicAdd(&hist[d >> 7], 1);
    }
  }
  __syncthreads();
  for (int b = t; b < NBUK; b += 256) {
    int h = hist[b];
    int g = h ? atomicAdd(&bcur[b], h) : 0;
    sbase[b] = rowptr[b << 7] + g;
  }
  __syncthreads();
#pragma unroll
  for (int j = 0; j < 16; ++j) {
    int e = e0 + j * 256 + t;
    if (e < NE) {
      int s = ei[e];
      int d = (int)d16[j];
      tmp[sbase[d >> 7] + (int)p16[j]] = ((unsigned)s << 16) | (unsigned)d;
    }
  }
}

// Phase 2: one block per bucket; LDS per-dst cursors; csr writes land in the
// bucket's ~16KB window (L2-resident).
__global__ __launch_bounds__(256) void k_fill2(const unsigned* __restrict__ tmp,
                                               const int* __restrict__ rowptr,
                                               int* __restrict__ csr) {
  __shared__ int cur[128];
  int b  = blockIdx.x;
  int t  = threadIdx.x;
  int n0 = b << 7;
  int n1 = n0 + 128; if (n1 > NN) n1 = NN;
  if (t < 128) cur[t] = 0;
  int beg = rowptr[n0];
  int end = rowptr[n1];
  __syncthreads();
  for (int i = beg + t; i < end; i += 256) {
    unsigned pk = tmp[i];
    int d = (int)(pk & 0xFFFFu);
    int s = (int)(pk >> 16);
    int p = atomicAdd(&cur[d - n0], 1);
    csr[rowptr[d] + p] = s;
  }
}

// ---------------- W1 -> W1^T bf16  ([512][128] f32 -> [128][512] bf16) ----------------

__global__ __launch_bounds__(256) void k_cvtw1(const float* __restrict__ W,
                                               unsigned short* __restrict__ Wt) {
  int i = blockIdx.x * 256 + threadIdx.x;
  if (i < FIN * H1F) {
    int k = i >> 7, c = i & 127;          // coalesced read of W[k][c]
    Wt[c * FIN + k] = f2bf(W[i]);
  }
}

// ---------------- GEMM1 (MFMA): hw1 = bf16(x @ W1) ----------------
// BM=64 rows x 128 cols per block, 4 waves (wave = 16 rows x 128 cols).
// K staged in 16 steps of 32. A converted f32->bf16 in-register.
// LDS rows padded to 80B (5-word stride) for conflict-free ds_read_b128.
// mfma(Wt_frag, x_frag): lane holds C[row=lane&15][col=f*16+(lane>>4)*4 + 0..3].

#define G1_ABUF 5120          // 64 rows * 80B
#define G1_BBUF 10240         // 128 cols * 80B
#define G1_BUF  (G1_ABUF + G1_BBUF)
#define G1_NSTEP 16

__global__ __launch_bounds__(256) void k_gemm1m(const float* __restrict__ X,
                                                const unsigned short* __restrict__ W1t,
                                                unsigned short* __restrict__ outb) {
  __shared__ char lds[2 * G1_BUF];
  int tid  = threadIdx.x;
  int row0 = blockIdx.x * 64;
  int w    = tid >> 6;
  int lane = tid & 63;

  // staging roles
  int ar = tid >> 2, aq = tid & 3;        // A: row ar, k-chunk aq (8 floats)
  int bc = tid >> 1, bh = tid & 1;        // B: col bc, half bh (16 bf16)

  float4 av0, av1;
  uint4  bu0, bu1;

  auto load_g = [&](int s) {
    int k0 = s * 32;
    int row = row0 + ar;
    av0 = make_float4(0.f, 0.f, 0.f, 0.f);
    av1 = av0;
    if (row < NN) {
      const float* gp = X + (size_t)row * FIN + k0 + aq * 8;
      av0 = *(const float4*)gp;
      av1 = *(const float4*)(gp + 4);
    }
    const uint4* bp = (const uint4*)(W1t + (size_t)bc * FIN + k0 + bh * 16);
    bu0 = bp[0];
    bu1 = bp[1];
  };
  auto store_l = [&](int buf) {
    char* Ab = lds + buf * G1_BUF;
    char* Bb = Ab + G1_ABUF;
    uint4 ap;
    ap.x = pack2bf(av0.x, av0.y); ap.y = pack2bf(av0.z, av0.w);
    ap.z = pack2bf(av1.x, av1.y); ap.w = pack2bf(av1.z, av1.w);
    *(uint4*)(Ab + ar * 80 + aq * 16) = ap;
    *(uint4*)(Bb + bc * 80 + bh * 32)      = bu0;
    *(uint4*)(Bb + bc * 80 + bh * 32 + 16) = bu1;
  };

  f32x4 acc[8];
#pragma unroll
  for (int f = 0; f < 8; ++f) acc[f] = (f32x4){0.f, 0.f, 0.f, 0.f};

  load_g(0);
  store_l(0);

  for (int s = 0; s < G1_NSTEP; ++s) {
    if (s + 1 < G1_NSTEP) load_g(s + 1);      // overlap HBM latency with MFMA
    __syncthreads();                           // buf[s&1] writes complete
    const char* Ab = lds + (s & 1) * G1_BUF;
    const char* Bb = Ab + G1_ABUF;
    bf16x8 xa = *(const bf16x8*)(Ab + (w * 16 + (lane & 15)) * 80 + (lane >> 4) * 16);
#pragma unroll
    for (int f = 0; f < 8; ++f) {
      bf16x8 bt = *(const bf16x8*)(Bb + (f * 16 + (lane & 15)) * 80 + (lane >> 4) * 16);
      acc[f] = __builtin_amdgcn_mfma_f32_16x16x32_bf16(bt, xa, acc[f], 0, 0, 0);
    }
    if (s + 1 < G1_NSTEP) store_l((s + 1) & 1);  // write-late into other buffer
  }

  int orow = row0 + w * 16 + (lane & 15);
  if (orow < NN) {
    size_t base = (size_t)orow * H1F;
#pragma unroll
    for (int f = 0; f < 8; ++f) {
      int col = f * 16 + (lane >> 4) * 4;
      uint2 pk;
      pk.x = pack2bf(acc[f][0], acc[f][1]);
      pk.y = pack2bf(acc[f][2], acc[f][3]);
      *(uint2*)(outb + base + col) = pk;       // 8B store, 8B-aligned
    }
  }
}

// ---------------- aggregation over bf16 feature table ----------------
// out[d] = dinv[d]*(sum_{s in N(d)} dinv[s]*feat[s] + dinv[d]*feat[d]) (+bias)
// one wave per dst node; 2 feats/lane packed in one uint (256B gather per edge).

template<bool BIAS, bool OUTBF>
__global__ __launch_bounds__(256) void k_aggb(const unsigned* __restrict__ feat,   // [NN][64] uints
                                              const int* __restrict__ rowptr,
                                              const int* __restrict__ csr,
                                              const float* __restrict__ dinv,
                                              const float* __restrict__ bias,
                                              void* __restrict__ out) {
  int gw   = (blockIdx.x * 256 + threadIdx.x) >> 6;   // dst node
  int lane = threadIdx.x & 63;
  if (gw >= NN) return;
  int beg = rowptr[gw], end = rowptr[gw + 1];
  float di = dinv[gw];
  float ax = 0.f, ay = 0.f;

  for (int e = beg; e < end; e += 64) {
    int cnt = end - e; if (cnt > 64) cnt = 64;
    int sv = 0; float wv = 0.f;
    if (lane < cnt) { sv = csr[e + lane]; wv = dinv[sv]; }
    int j = 0;
    for (; j + 4 <= cnt; j += 4) {
      int s0 = __shfl(sv, j),     s1 = __shfl(sv, j + 1);
      int s2 = __shfl(sv, j + 2), s3 = __shfl(sv, j + 3);
      float w0 = __shfl(wv, j),     w1 = __shfl(wv, j + 1);
      float w2 = __shfl(wv, j + 2), w3 = __shfl(wv, j + 3);
      unsigned v0 = feat[(size_t)s0 * 64 + lane];
      unsigned v1 = feat[(size_t)s1 * 64 + lane];
      unsigned v2 = feat[(size_t)s2 * 64 + lane];
      unsigned v3 = feat[(size_t)s3 * 64 + lane];
      ax += w0 * bflo(v0); ay += w0 * bfhi(v0);
      ax += w1 * bflo(v1); ay += w1 * bfhi(v1);
      ax += w2 * bflo(v2); ay += w2 * bfhi(v2);
      ax += w3 * bflo(v3); ay += w3 * bfhi(v3);
    }
    for (; j < cnt; ++j) {
      int s = __shfl(sv, j);
      float w = __shfl(wv, j);
      unsigned v = feat[(size_t)s * 64 + lane];
      ax += w * bflo(v); ay += w * bfhi(v);
    }
  }
  // self loop
  unsigned vd = feat[(size_t)gw * 64 + lane];
  ax = di * (ax + di * bflo(vd));
  ay = di * (ay + di * bfhi(vd));
  if (BIAS) { ax += bias[lane * 2]; ay += bias[lane * 2 + 1]; }
  if (OUTBF) {
    ((unsigned*)out)[(size_t)gw * 64 + lane] = pack2bf(ax, ay);
  } else {
    ((float2*)out)[(size_t)gw * 64 + lane] = make_float2(ax, ay);
  }
}

// ---------------- GEMM2 fused: [mu|logvar] = g @ [W2|W3] + [b2|b3]; z = eps*exp(logvar)+mu ----------------

__global__ __launch_bounds__(256) void k_gemm2z(const float* __restrict__ G,
                                                const float* __restrict__ W2,
                                                const float* __restrict__ W3,
                                                const float* __restrict__ b2,
                                                const float* __restrict__ b3,
                                                const float* __restrict__ eps,
                                                float* __restrict__ z) {
  __shared__ float As[64][32];
  __shared__ float Bs[32][128];
  int tid  = threadIdx.x;
  int row0 = blockIdx.x * 64;
  int tcol = tid & 31;
  int trow = (tid >> 5) * 8;
  float acc[8][4] = {};
  for (int k0 = 0; k0 < H1F; k0 += 32) {
#pragma unroll
    for (int i = 0; i < 2; ++i) {
      int f = tid + i * 256;
      int r = f >> 3, kq = (f & 7) * 4;
      float4 v = make_float4(0.f, 0.f, 0.f, 0.f);
      if (row0 + r < NN) v = *(const float4*)&G[(size_t)(row0 + r) * H1F + k0 + kq];
      *(float4*)&As[r][kq] = v;
    }
#pragma unroll
    for (int i = 0; i < 4; ++i) {
      int f = tid + i * 256;
      int r = f >> 5, c = (f & 31) * 4;
      float4 v;
      if (c < 64) v = *(const float4*)&W2[(size_t)(k0 + r) * 64 + c];
      else        v = *(const float4*)&W3[(size_t)(k0 + r) * 64 + (c - 64)];
      *(float4*)&Bs[r][c] = v;
    }
    __syncthreads();
#pragma unroll
    for (int kk = 0; kk < 32; ++kk) {
      float a[8];
#pragma unroll
      for (int r = 0; r < 8; ++r) a[r] = As[trow + r][kk];
      float b0 = Bs[kk][tcol], b1v = Bs[kk][tcol + 32];
      float b2v = Bs[kk][tcol + 64], b3v = Bs[kk][tcol + 96];
#pragma unroll
      for (int r = 0; r < 8; ++r) {
        acc[r][0] += a[r] * b0;  acc[r][1] += a[r] * b1v;
        acc[r][2] += a[r] * b2v; acc[r][3] += a[r] * b3v;
      }
    }
    __syncthreads();
  }
  float bb2a = b2[tcol], bb2b = b2[tcol + 32];
  float bb3a = b3[tcol], bb3b = b3[tcol + 32];
#pragma unroll
  for (int r = 0; r < 8; ++r) {
    int row = row0 + trow + r;
    if (row < NN) {
      float mu0 = acc[r][0] + bb2a;
      float mu1 = acc[r][1] + bb2b;
      float lv0 = acc[r][2] + bb3a;
      float lv1 = acc[r][3] + bb3b;
      size_t base = (size_t)row * 64;
      z[base + tcol]      = eps[base + tcol]      * __expf(lv0) + mu0;
      z[base + tcol + 32] = eps[base + tcol + 32] * __expf(lv1) + mu1;
    }
  }
}

// ---------------- launch ----------------

extern "C" void kernel_launch(void* const* d_in, const int* in_sizes, int n_in,
                              void* d_out, int out_size, void* d_ws, size_t ws_size,
                              hipStream_t stream) {
  const float* x   = (const float*)d_in[0];
  const int*   ei  = (const int*)  d_in[1];
  const float* W1  = (const float*)d_in[2];
  const float* b1  = (const float*)d_in[3];
  const float* W2  = (const float*)d_in[4];
  const float* b2  = (const float*)d_in[5];
  const float* W3  = (const float*)d_in[6];
  const float* b3  = (const float*)d_in[7];
  const float* eps = (const float*)d_in[8];
  float* z = (float*)d_out;

  char* ws = (char*)d_ws;
  size_t o = 0;
  auto alloc = [&](size_t bytes) -> void* {
    void* p = ws + o;
    o = (o + bytes + 255) & ~(size_t)255;
    return p;
  };
  int*   deg    = (int*)  alloc((size_t)NN * 4);
  int*   rowptr = (int*)  alloc((size_t)(NN + 1) * 4);
  int*   bcur   = (int*)  alloc((size_t)NBUK * 4);
  int*   csums  = (int*)  alloc((size_t)NCHUNK * 4);
  float* dinv   = (float*)alloc((size_t)NN * 4);
  int*   csr    = (int*)  alloc((size_t)NE * 4);
  unsigned short* W1t  = (unsigned short*)alloc((size_t)H1F * FIN * 2);  // bf16 W1^T
  unsigned short* hw1b = (unsigned short*)alloc((size_t)NN * H1F * 2);   // bf16 x@W1
  unsigned short* h1b  = (unsigned short*)alloc((size_t)NN * H1F * 2);   // bf16 h1
  float* g = (float*)alloc((size_t)NN * H1F * 4);                        // f32 Agg(h1)
  unsigned* tmp = (unsigned*)g;   // bucketed edges; dead before agg2 writes g

  k_init   <<<(NN + 255) / 256, 256, 0, stream>>>(deg, bcur);
  k_count  <<<(NE + 255) / 256, 256, 0, stream>>>(ei, deg);
  k_partial<<<NCHUNK, 256, 0, stream>>>(deg, csums, dinv);
  k_top    <<<1, 64, 0, stream>>>(csums, rowptr);
  k_scan   <<<NCHUNK, 256, 0, stream>>>(deg, csums, rowptr);
  k_bin    <<<NBIN, 256, 0, stream>>>(ei, rowptr, bcur, tmp);
  k_fill2  <<<NBUK, 256, 0, stream>>>(tmp, rowptr, csr);
  k_cvtw1  <<<(FIN * H1F + 255) / 256, 256, 0, stream>>>(W1, W1t);

  k_gemm1m <<<(NN + 63) / 64, 256, 0, stream>>>(x, W1t, hw1b);
  k_aggb<true,  true ><<<(NN + 3) / 4, 256, 0, stream>>>((const unsigned*)hw1b, rowptr, csr, dinv, b1, (void*)h1b);
  k_aggb<false, false><<<(NN + 3) / 4, 256, 0, stream>>>((const unsigned*)h1b,  rowptr, csr, dinv, nullptr, (void*)g);
  k_gemm2z <<<(NN + 63) / 64, 256, 0, stream>>>(g, W2, W3, b2, b3, eps, z);
}

// Round 6
// 216.999 us; speedup vs baseline: 1.6216x; 1.3501x over previous
//
#include <hip/hip_runtime.h>
#include <math.h>

#define NN   50000
#define NE   1600000
#define FIN  512
#define H1F  128
#define NBUK  391    // ceil(NN/128)  — dst-bucket = 128 consecutive nodes
#define BIN_EPB 4096 // edges per binning block (16 per thread)
#define NBIN  391    // ceil(NE/BIN_EPB)

typedef __attribute__((ext_vector_type(8))) short bf16x8;
typedef __attribute__((ext_vector_type(4))) float f32x4;

// ---------------- bf16 helpers ----------------
__device__ __forceinline__ float bflo(unsigned v) { return __uint_as_float(v << 16); }
__device__ __forceinline__ float bfhi(unsigned v) { return __uint_as_float(v & 0xffff0000u); }
__device__ __forceinline__ unsigned short f2bf(float f) {
  unsigned u = __float_as_uint(f);
  u += 0x7fffu + ((u >> 16) & 1u);   // round-to-nearest-even
  return (unsigned short)(u >> 16);
}
__device__ __forceinline__ unsigned pack2bf(float a, float b) {
  return (unsigned)f2bf(a) | ((unsigned)f2bf(b) << 16);
}

// ---------------- CSR build: radix partition, ZERO global atomics ----------------

// 1) per-block LDS histogram over dst-buckets -> gh[bucket][block]
__global__ __launch_bounds__(256) void k_binhist(const int* __restrict__ ei,
                                                 int* __restrict__ gh) {
  __shared__ int hist[NBUK];
  int t  = threadIdx.x;
  int e0 = blockIdx.x * BIN_EPB;
  for (int b = t; b < NBUK; b += 256) hist[b] = 0;
  __syncthreads();
#pragma unroll
  for (int j = 0; j < 16; ++j) {
    int e = e0 + j * 256 + t;
    if (e < NE) atomicAdd(&hist[ei[NE + e] >> 7], 1);
  }
  __syncthreads();
  for (int b = t; b < NBUK; b += 256) gh[(size_t)b * NBIN + blockIdx.x] = hist[b];
}

// 2) exclusive scan of each bucket row over blocks; row total -> btot
__global__ __launch_bounds__(64) void k_rowscan(int* __restrict__ gh,
                                                int* __restrict__ btot) {
  int row  = blockIdx.x;
  int lane = threadIdx.x;
  int* g = gh + (size_t)row * NBIN;
  int carry = 0;
  for (int c = 0; c < (NBIN + 63) / 64; ++c) {
    int idx = c * 64 + lane;
    int v = (idx < NBIN) ? g[idx] : 0;
    int incl = v;
#pragma unroll
    for (int off = 1; off < 64; off <<= 1) {
      int u = __shfl_up(incl, off, 64);
      if (lane >= off) incl += u;
    }
    if (idx < NBIN) g[idx] = carry + (incl - v);
    carry += __shfl(incl, 63, 64);
  }
  if (lane == 0) btot[row] = carry;
}

// 3) exclusive scan over bucket totals -> bbase[0..NBUK], bbase[NBUK]=NE
__global__ __launch_bounds__(512) void k_bscan(const int* __restrict__ btot,
                                               int* __restrict__ bbase) {
  __shared__ int ts[512];
  int t = threadIdx.x;
  int v = (t < NBUK) ? btot[t] : 0;
  ts[t] = v;
  __syncthreads();
  for (int off = 1; off < 512; off <<= 1) {
    int val = ts[t];
    int add = (t >= off) ? ts[t - off] : 0;
    __syncthreads();
    ts[t] = val + add;
    __syncthreads();
  }
  if (t < NBUK) bbase[t] = ts[t] - v;
  if (t == NBUK - 1) bbase[NBUK] = ts[t];   // == NE
}

// 4) scatter edges into bucket runs; base = bbase[b] + gh[b][block] (no atomics)
__global__ __launch_bounds__(256) void k_binscat(const int* __restrict__ ei,
                                                 const int* __restrict__ gh,
                                                 const int* __restrict__ bbase,
                                                 unsigned* __restrict__ tmp) {
  __shared__ int hist[NBUK];
  __shared__ int sbase[NBUK];
  int t  = threadIdx.x;
  int e0 = blockIdx.x * BIN_EPB;
  for (int b = t; b < NBUK; b += 256) hist[b] = 0;
  __syncthreads();

  unsigned short d16[16];
  unsigned short p16[16];
#pragma unroll
  for (int j = 0; j < 16; ++j) {
    int e = e0 + j * 256 + t;
    d16[j] = 0xFFFFu;
    if (e < NE) {
      int d = ei[NE + e];
      d16[j] = (unsigned short)d;
      p16[j] = (unsigned short)atomicAdd(&hist[d >> 7], 1);
    }
  }
  __syncthreads();
  for (int b = t; b < NBUK; b += 256)
    sbase[b] = bbase[b] + gh[(size_t)b * NBIN + blockIdx.x];
  __syncthreads();
#pragma unroll
  for (int j = 0; j < 16; ++j) {
    int e = e0 + j * 256 + t;
    if (e < NE) {
      int s = ei[e];
      int d = (int)d16[j];
      tmp[sbase[d >> 7] + (int)p16[j]] = ((unsigned)s << 16) | (unsigned)d;
    }
  }
}

// 5) per bucket: LDS degree count + scan -> rowptr & dinv; LDS-cursor csr scatter.
__global__ __launch_bounds__(256) void k_fill2x(const unsigned* __restrict__ tmp,
                                                const int* __restrict__ bbase,
                                                int* __restrict__ rowptr,
                                                float* __restrict__ dinv,
                                                int* __restrict__ csr) {
  __shared__ int cnt[128];
  __shared__ int lofs[128];
  __shared__ int cur[128];
  __shared__ int ts[256];
  int b  = blockIdx.x;
  int t  = threadIdx.x;
  int n0 = b << 7;
  int beg = bbase[b];
  int end = bbase[b + 1];
  if (t < 128) { cnt[t] = 0; cur[t] = 0; }
  __syncthreads();
  for (int i = beg + t; i < end; i += 256)
    atomicAdd(&cnt[tmp[i] & 0xFFFFu & 127], 1);   // d - n0 == d & 127
  __syncthreads();
  int v = (t < 128) ? cnt[t] : 0;
  ts[t] = v;
  __syncthreads();
  for (int off = 1; off < 128; off <<= 1) {
    int val = ts[t];
    int add = (t >= off) ? ts[t - off] : 0;
    __syncthreads();
    ts[t] = val + add;
    __syncthreads();
  }
  if (t < 128) {
    int excl = ts[t] - v;
    lofs[t] = beg + excl;
    int n = n0 + t;
    if (n < NN) {
      rowptr[n] = beg + excl;
      dinv[n]   = rsqrtf((float)(v + 1));   // self-loop included
    }
  }
  if (b == NBUK - 1 && t == 0) rowptr[NN] = end;
  __syncthreads();
  for (int i = beg + t; i < end; i += 256) {
    unsigned pk = tmp[i];
    int dl = (int)(pk & 127u);
    int s  = (int)(pk >> 16);
    int p  = atomicAdd(&cur[dl], 1);
    csr[lofs[dl] + p] = s;
  }
}

// ---------------- W1 -> W1^T bf16  ([512][128] f32 -> [128][512] bf16) ----------------

__global__ __launch_bounds__(256) void k_cvtw1(const float* __restrict__ W,
                                               unsigned short* __restrict__ Wt) {
  int i = blockIdx.x * 256 + threadIdx.x;
  if (i < FIN * H1F) {
    int k = i >> 7, c = i & 127;          // coalesced read of W[k][c]
    Wt[c * FIN + k] = f2bf(W[i]);
  }
}

// ---------------- GEMM1 (MFMA): hw1 = bf16(x @ W1) ----------------
// BM=64 rows x 128 cols per block, 4 waves (wave = 16 rows x 128 cols).
// LDS rows padded to 80B; reg-prefetch double-buffer, one barrier per K-step.

#define G1_ABUF 5120          // 64 rows * 80B
#define G1_BBUF 10240         // 128 cols * 80B
#define G1_BUF  (G1_ABUF + G1_BBUF)
#define G1_NSTEP 16

__global__ __launch_bounds__(256) void k_gemm1m(const float* __restrict__ X,
                                                const unsigned short* __restrict__ W1t,
                                                unsigned short* __restrict__ outb) {
  __shared__ char lds[2 * G1_BUF];
  int tid  = threadIdx.x;
  int row0 = blockIdx.x * 64;
  int w    = tid >> 6;
  int lane = tid & 63;

  int ar = tid >> 2, aq = tid & 3;        // A: row ar, k-chunk aq (8 floats)
  int bc = tid >> 1, bh = tid & 1;        // B: col bc, half bh (16 bf16)

  float4 av0, av1;
  uint4  bu0, bu1;

  auto load_g = [&](int s) {
    int k0 = s * 32;
    int row = row0 + ar;
    av0 = make_float4(0.f, 0.f, 0.f, 0.f);
    av1 = av0;
    if (row < NN) {
      const float* gp = X + (size_t)row * FIN + k0 + aq * 8;
      av0 = *(const float4*)gp;
      av1 = *(const float4*)(gp + 4);
    }
    const uint4* bp = (const uint4*)(W1t + (size_t)bc * FIN + k0 + bh * 16);
    bu0 = bp[0];
    bu1 = bp[1];
  };
  auto store_l = [&](int buf) {
    char* Ab = lds + buf * G1_BUF;
    char* Bb = Ab + G1_ABUF;
    uint4 ap;
    ap.x = pack2bf(av0.x, av0.y); ap.y = pack2bf(av0.z, av0.w);
    ap.z = pack2bf(av1.x, av1.y); ap.w = pack2bf(av1.z, av1.w);
    *(uint4*)(Ab + ar * 80 + aq * 16) = ap;
    *(uint4*)(Bb + bc * 80 + bh * 32)      = bu0;
    *(uint4*)(Bb + bc * 80 + bh * 32 + 16) = bu1;
  };

  f32x4 acc[8];
#pragma unroll
  for (int f = 0; f < 8; ++f) acc[f] = (f32x4){0.f, 0.f, 0.f, 0.f};

  load_g(0);
  store_l(0);

  for (int s = 0; s < G1_NSTEP; ++s) {
    if (s + 1 < G1_NSTEP) load_g(s + 1);
    __syncthreads();
    const char* Ab = lds + (s & 1) * G1_BUF;
    const char* Bb = Ab + G1_ABUF;
    bf16x8 xa = *(const bf16x8*)(Ab + (w * 16 + (lane & 15)) * 80 + (lane >> 4) * 16);
#pragma unroll
    for (int f = 0; f < 8; ++f) {
      bf16x8 bt = *(const bf16x8*)(Bb + (f * 16 + (lane & 15)) * 80 + (lane >> 4) * 16);
      acc[f] = __builtin_amdgcn_mfma_f32_16x16x32_bf16(bt, xa, acc[f], 0, 0, 0);
    }
    if (s + 1 < G1_NSTEP) store_l((s + 1) & 1);
  }

  int orow = row0 + w * 16 + (lane & 15);
  if (orow < NN) {
    size_t base = (size_t)orow * H1F;
#pragma unroll
    for (int f = 0; f < 8; ++f) {
      int col = f * 16 + (lane >> 4) * 4;
      uint2 pk;
      pk.x = pack2bf(acc[f][0], acc[f][1]);
      pk.y = pack2bf(acc[f][2], acc[f][3]);
      *(uint2*)(outb + base + col) = pk;
    }
  }
}

// ---------------- aggregation over bf16 feature table ----------------

template<bool BIAS, bool OUTBF>
__global__ __launch_bounds__(256) void k_aggb(const unsigned* __restrict__ feat,   // [NN][64] uints
                                              const int* __restrict__ rowptr,
                                              const int* __restrict__ csr,
                                              const float* __restrict__ dinv,
                                              const float* __restrict__ bias,
                                              void* __restrict__ out) {
  int gw   = (blockIdx.x * 256 + threadIdx.x) >> 6;   // dst node
  int lane = threadIdx.x & 63;
  if (gw >= NN) return;
  int beg = rowptr[gw], end = rowptr[gw + 1];
  float di = dinv[gw];
  float ax = 0.f, ay = 0.f;

  for (int e = beg; e < end; e += 64) {
    int cnt = end - e; if (cnt > 64) cnt = 64;
    int sv = 0; float wv = 0.f;
    if (lane < cnt) { sv = csr[e + lane]; wv = dinv[sv]; }
    int j = 0;
    for (; j + 4 <= cnt; j += 4) {
      int s0 = __shfl(sv, j),     s1 = __shfl(sv, j + 1);
      int s2 = __shfl(sv, j + 2), s3 = __shfl(sv, j + 3);
      float w0 = __shfl(wv, j),     w1 = __shfl(wv, j + 1);
      float w2 = __shfl(wv, j + 2), w3 = __shfl(wv, j + 3);
      unsigned v0 = feat[(size_t)s0 * 64 + lane];
      unsigned v1 = feat[(size_t)s1 * 64 + lane];
      unsigned v2 = feat[(size_t)s2 * 64 + lane];
      unsigned v3 = feat[(size_t)s3 * 64 + lane];
      ax += w0 * bflo(v0); ay += w0 * bfhi(v0);
      ax += w1 * bflo(v1); ay += w1 * bfhi(v1);
      ax += w2 * bflo(v2); ay += w2 * bfhi(v2);
      ax += w3 * bflo(v3); ay += w3 * bfhi(v3);
    }
    for (; j < cnt; ++j) {
      int s = __shfl(sv, j);
      float w = __shfl(wv, j);
      unsigned v = feat[(size_t)s * 64 + lane];
      ax += w * bflo(v); ay += w * bfhi(v);
    }
  }
  // self loop
  unsigned vd = feat[(size_t)gw * 64 + lane];
  ax = di * (ax + di * bflo(vd));
  ay = di * (ay + di * bfhi(vd));
  if (BIAS) { ax += bias[lane * 2]; ay += bias[lane * 2 + 1]; }
  if (OUTBF) {
    ((unsigned*)out)[(size_t)gw * 64 + lane] = pack2bf(ax, ay);
  } else {
    ((float2*)out)[(size_t)gw * 64 + lane] = make_float2(ax, ay);
  }
}

// ---------------- GEMM2 fused: [mu|logvar] = g @ [W2|W3] + [b2|b3]; z = eps*exp(logvar)+mu ----------------

__global__ __launch_bounds__(256) void k_gemm2z(const float* __restrict__ G,
                                                const float* __restrict__ W2,
                                                const float* __restrict__ W3,
                                                const float* __restrict__ b2,
                                                const float* __restrict__ b3,
                                                const float* __restrict__ eps,
                                                float* __restrict__ z) {
  __shared__ float As[64][32];
  __shared__ float Bs[32][128];
  int tid  = threadIdx.x;
  int row0 = blockIdx.x * 64;
  int tcol = tid & 31;
  int trow = (tid >> 5) * 8;
  float acc[8][4] = {};
  for (int k0 = 0; k0 < H1F; k0 += 32) {
#pragma unroll
    for (int i = 0; i < 2; ++i) {
      int f = tid + i * 256;
      int r = f >> 3, kq = (f & 7) * 4;
      float4 v = make_float4(0.f, 0.f, 0.f, 0.f);
      if (row0 + r < NN) v = *(const float4*)&G[(size_t)(row0 + r) * H1F + k0 + kq];
      *(float4*)&As[r][kq] = v;
    }
#pragma unroll
    for (int i = 0; i < 4; ++i) {
      int f = tid + i * 256;
      int r = f >> 5, c = (f & 31) * 4;
      float4 v;
      if (c < 64) v = *(const float4*)&W2[(size_t)(k0 + r) * 64 + c];
      else        v = *(const float4*)&W3[(size_t)(k0 + r) * 64 + (c - 64)];
      *(float4*)&Bs[r][c] = v;
    }
    __syncthreads();
#pragma unroll
    for (int kk = 0; kk < 32; ++kk) {
      float a[8];
#pragma unroll
      for (int r = 0; r < 8; ++r) a[r] = As[trow + r][kk];
      float b0 = Bs[kk][tcol], b1v = Bs[kk][tcol + 32];
      float b2v = Bs[kk][tcol + 64], b3v = Bs[kk][tcol + 96];
#pragma unroll
      for (int r = 0; r < 8; ++r) {
        acc[r][0] += a[r] * b0;  acc[r][1] += a[r] * b1v;
        acc[r][2] += a[r] * b2v; acc[r][3] += a[r] * b3v;
      }
    }
    __syncthreads();
  }
  float bb2a = b2[tcol], bb2b = b2[tcol + 32];
  float bb3a = b3[tcol], bb3b = b3[tcol + 32];
#pragma unroll
  for (int r = 0; r < 8; ++r) {
    int row = row0 + trow + r;
    if (row < NN) {
      float mu0 = acc[r][0] + bb2a;
      float mu1 = acc[r][1] + bb2b;
      float lv0 = acc[r][2] + bb3a;
      float lv1 = acc[r][3] + bb3b;
      size_t base = (size_t)row * 64;
      z[base + tcol]      = eps[base + tcol]      * __expf(lv0) + mu0;
      z[base + tcol + 32] = eps[base + tcol + 32] * __expf(lv1) + mu1;
    }
  }
}

// ---------------- launch ----------------

extern "C" void kernel_launch(void* const* d_in, const int* in_sizes, int n_in,
                              void* d_out, int out_size, void* d_ws, size_t ws_size,
                              hipStream_t stream) {
  const float* x   = (const float*)d_in[0];
  const int*   ei  = (const int*)  d_in[1];
  const float* W1  = (const float*)d_in[2];
  const float* b1  = (const float*)d_in[3];
  const float* W2  = (const float*)d_in[4];
  const float* b2  = (const float*)d_in[5];
  const float* W3  = (const float*)d_in[6];
  const float* b3  = (const float*)d_in[7];
  const float* eps = (const float*)d_in[8];
  float* z = (float*)d_out;

  char* ws = (char*)d_ws;
  size_t o = 0;
  auto alloc = [&](size_t bytes) -> void* {
    void* p = ws + o;
    o = (o + bytes + 255) & ~(size_t)255;
    return p;
  };
  int*   gh     = (int*)  alloc((size_t)NBUK * NBIN * 4);
  int*   btot   = (int*)  alloc((size_t)NBUK * 4);
  int*   bbase  = (int*)  alloc((size_t)(NBUK + 1) * 4);
  int*   rowptr = (int*)  alloc((size_t)(NN + 1) * 4);
  float* dinv   = (float*)alloc((size_t)NN * 4);
  int*   csr    = (int*)  alloc((size_t)NE * 4);
  unsigned short* W1t  = (unsigned short*)alloc((size_t)H1F * FIN * 2);  // bf16 W1^T
  unsigned short* hw1b = (unsigned short*)alloc((size_t)NN * H1F * 2);   // bf16 x@W1
  unsigned short* h1b  = (unsigned short*)alloc((size_t)NN * H1F * 2);   // bf16 h1
  float* g = (float*)alloc((size_t)NN * H1F * 4);                        // f32 Agg(h1)
  unsigned* tmp = (unsigned*)g;   // bucketed edges; dead before agg2 writes g

  k_binhist<<<NBIN, 256, 0, stream>>>(ei, gh);
  k_rowscan<<<NBUK, 64, 0, stream>>>(gh, btot);
  k_bscan  <<<1, 512, 0, stream>>>(btot, bbase);
  k_binscat<<<NBIN, 256, 0, stream>>>(ei, gh, bbase, tmp);
  k_fill2x <<<NBUK, 256, 0, stream>>>(tmp, bbase, rowptr, dinv, csr);
  k_cvtw1  <<<(FIN * H1F + 255) / 256, 256, 0, stream>>>(W1, W1t);

  k_gemm1m <<<(NN + 63) / 64, 256, 0, stream>>>(x, W1t, hw1b);
  k_aggb<true,  true ><<<(NN + 3) / 4, 256, 0, stream>>>((const unsigned*)hw1b, rowptr, csr, dinv, b1, (void*)h1b);
  k_aggb<false, false><<<(NN + 3) / 4, 256, 0, stream>>>((const unsigned*)h1b,  rowptr, csr, dinv, nullptr, (void*)g);
  k_gemm2z <<<(NN + 63) / 64, 256, 0, stream>>>(g, W2, W3, b2, b3, eps, z);
}

// Round 7
// 188.046 us; speedup vs baseline: 1.8713x; 1.1540x over previous
//
#include <hip/hip_runtime.h>
#include <math.h>

#define NN   50000
#define NE   1600000
#define FIN  512
#define H1F  128
#define NBUK  391    // ceil(NN/128)  — dst-bucket = 128 consecutive nodes
#define BIN_EPB 4096 // edges per binning block (16 per thread)
#define NBIN  391    // ceil(NE/BIN_EPB)

typedef __attribute__((ext_vector_type(8))) short bf16x8;
typedef __attribute__((ext_vector_type(4))) float f32x4;

// ---------------- bf16 helpers ----------------
__device__ __forceinline__ float bflo(unsigned v) { return __uint_as_float(v << 16); }
__device__ __forceinline__ float bfhi(unsigned v) { return __uint_as_float(v & 0xffff0000u); }
__device__ __forceinline__ unsigned short f2bf(float f) {
  unsigned u = __float_as_uint(f);
  u += 0x7fffu + ((u >> 16) & 1u);   // round-to-nearest-even
  return (unsigned short)(u >> 16);
}
__device__ __forceinline__ unsigned pack2bf(float a, float b) {
  return (unsigned)f2bf(a) | ((unsigned)f2bf(b) << 16);
}

// ---------------- CSR build: radix partition, ZERO global atomics ----------------

__global__ __launch_bounds__(256) void k_binhist(const int* __restrict__ ei,
                                                 int* __restrict__ gh) {
  __shared__ int hist[NBUK];
  int t  = threadIdx.x;
  int e0 = blockIdx.x * BIN_EPB;
  for (int b = t; b < NBUK; b += 256) hist[b] = 0;
  __syncthreads();
#pragma unroll
  for (int j = 0; j < 16; ++j) {
    int e = e0 + j * 256 + t;
    if (e < NE) atomicAdd(&hist[ei[NE + e] >> 7], 1);
  }
  __syncthreads();
  for (int b = t; b < NBUK; b += 256) gh[(size_t)b * NBIN + blockIdx.x] = hist[b];
}

__global__ __launch_bounds__(64) void k_rowscan(int* __restrict__ gh,
                                                int* __restrict__ btot) {
  int row  = blockIdx.x;
  int lane = threadIdx.x;
  int* g = gh + (size_t)row * NBIN;
  int carry = 0;
  for (int c = 0; c < (NBIN + 63) / 64; ++c) {
    int idx = c * 64 + lane;
    int v = (idx < NBIN) ? g[idx] : 0;
    int incl = v;
#pragma unroll
    for (int off = 1; off < 64; off <<= 1) {
      int u = __shfl_up(incl, off, 64);
      if (lane >= off) incl += u;
    }
    if (idx < NBIN) g[idx] = carry + (incl - v);
    carry += __shfl(incl, 63, 64);
  }
  if (lane == 0) btot[row] = carry;
}

__global__ __launch_bounds__(512) void k_bscan(const int* __restrict__ btot,
                                               int* __restrict__ bbase) {
  __shared__ int ts[512];
  int t = threadIdx.x;
  int v = (t < NBUK) ? btot[t] : 0;
  ts[t] = v;
  __syncthreads();
  for (int off = 1; off < 512; off <<= 1) {
    int val = ts[t];
    int add = (t >= off) ? ts[t - off] : 0;
    __syncthreads();
    ts[t] = val + add;
    __syncthreads();
  }
  if (t < NBUK) bbase[t] = ts[t] - v;
  if (t == NBUK - 1) bbase[NBUK] = ts[t];   // == NE
}

__global__ __launch_bounds__(256) void k_binscat(const int* __restrict__ ei,
                                                 const int* __restrict__ gh,
                                                 const int* __restrict__ bbase,
                                                 unsigned* __restrict__ tmp) {
  __shared__ int hist[NBUK];
  __shared__ int sbase[NBUK];
  int t  = threadIdx.x;
  int e0 = blockIdx.x * BIN_EPB;
  for (int b = t; b < NBUK; b += 256) hist[b] = 0;
  __syncthreads();

  unsigned short d16[16];
  unsigned short p16[16];
#pragma unroll
  for (int j = 0; j < 16; ++j) {
    int e = e0 + j * 256 + t;
    d16[j] = 0xFFFFu;
    if (e < NE) {
      int d = ei[NE + e];
      d16[j] = (unsigned short)d;
      p16[j] = (unsigned short)atomicAdd(&hist[d >> 7], 1);
    }
  }
  __syncthreads();
  for (int b = t; b < NBUK; b += 256)
    sbase[b] = bbase[b] + gh[(size_t)b * NBIN + blockIdx.x];
  __syncthreads();
#pragma unroll
  for (int j = 0; j < 16; ++j) {
    int e = e0 + j * 256 + t;
    if (e < NE) {
      int s = ei[e];
      int d = (int)d16[j];
      tmp[sbase[d >> 7] + (int)p16[j]] = ((unsigned)s << 16) | (unsigned)d;
    }
  }
}

__global__ __launch_bounds__(256) void k_fill2x(const unsigned* __restrict__ tmp,
                                                const int* __restrict__ bbase,
                                                int* __restrict__ rowptr,
                                                float* __restrict__ dinv,
                                                int* __restrict__ csr) {
  __shared__ int cnt[128];
  __shared__ int lofs[128];
  __shared__ int cur[128];
  __shared__ int ts[256];
  int b  = blockIdx.x;
  int t  = threadIdx.x;
  int n0 = b << 7;
  int beg = bbase[b];
  int end = bbase[b + 1];
  if (t < 128) { cnt[t] = 0; cur[t] = 0; }
  __syncthreads();
  for (int i = beg + t; i < end; i += 256)
    atomicAdd(&cnt[tmp[i] & 127u], 1);   // d - n0 == d & 127
  __syncthreads();
  int v = (t < 128) ? cnt[t] : 0;
  ts[t] = v;
  __syncthreads();
  for (int off = 1; off < 128; off <<= 1) {
    int val = ts[t];
    int add = (t >= off) ? ts[t - off] : 0;
    __syncthreads();
    ts[t] = val + add;
    __syncthreads();
  }
  if (t < 128) {
    int excl = ts[t] - v;
    lofs[t] = beg + excl;
    int n = n0 + t;
    if (n < NN) {
      rowptr[n] = beg + excl;
      dinv[n]   = rsqrtf((float)(v + 1));   // self-loop included
    }
  }
  if (b == NBUK - 1 && t == 0) rowptr[NN] = end;
  __syncthreads();
  for (int i = beg + t; i < end; i += 256) {
    unsigned pk = tmp[i];
    int dl = (int)(pk & 127u);
    int s  = (int)(pk >> 16);
    int p  = atomicAdd(&cur[dl], 1);
    csr[lofs[dl] + p] = s;
  }
}

// ---------------- weight repack: fragment-order bf16 ----------------
// W1f chunk (s*512 + f*64 + lane) = 16B = W1t[row=f*16+(lane&15)][k=s*32+(lane>>4)*8 ..+7]

__global__ __launch_bounds__(256) void k_cvtw1f(const float* __restrict__ W,
                                                unsigned short* __restrict__ W1f) {
  int i = blockIdx.x * 256 + threadIdx.x;   // 8192 chunks
  if (i >= 16 * 8 * 64) return;
  int s = i >> 9, rem = i & 511, f = rem >> 6, lane = rem & 63;
  int row = f * 16 + (lane & 15);
  int kb  = s * 32 + (lane >> 4) * 8;
  unsigned short c8[8];
#pragma unroll
  for (int j = 0; j < 8; ++j) c8[j] = f2bf(W[(size_t)(kb + j) * H1F + row]);
  *(uint4*)&W1f[(size_t)i * 8] = *(uint4*)c8;
}

// W23f: B = [W2|W3]^T fragment order; rows 0..63 = W2 cols, 64..127 = W3 cols; K=128.
__global__ __launch_bounds__(256) void k_cvtw23f(const float* __restrict__ W2,
                                                 const float* __restrict__ W3,
                                                 unsigned short* __restrict__ Wf) {
  int i = blockIdx.x * 256 + threadIdx.x;   // 2048 chunks
  if (i >= 4 * 8 * 64) return;
  int s = i >> 9, rem = i & 511, f = rem >> 6, lane = rem & 63;
  int row = f * 16 + (lane & 15);
  int kb  = s * 32 + (lane >> 4) * 8;
  const float* Wsrc = (row < 64) ? W2 : W3;
  int c = row & 63;
  unsigned short c8[8];
#pragma unroll
  for (int j = 0; j < 8; ++j) c8[j] = f2bf(Wsrc[(size_t)(kb + j) * 64 + c]);
  *(uint4*)&Wf[(size_t)i * 8] = *(uint4*)c8;
}

// ---------------- GEMM1 (MFMA): hw1 = bf16(x @ W1) ----------------
// B: fragment-order W1f -> linear LDS copy (conflict-free write+read).
// A: 80B-padded rows (conflict-free fragment reads).

#define G1_ABUF 5120                  // 64 rows * 80B
#define G1_BBUF 8192                  // 512 chunks * 16B
#define G1_BUF  (G1_ABUF + G1_BBUF)
#define G1_NSTEP 16

__global__ __launch_bounds__(256) void k_gemm1m(const float* __restrict__ X,
                                                const uint4* __restrict__ W1fv,
                                                unsigned short* __restrict__ outb) {
  __shared__ char lds[2 * G1_BUF];
  int tid  = threadIdx.x;
  int row0 = blockIdx.x * 64;
  int w    = tid >> 6;
  int lane = tid & 63;

  int ar = tid >> 2, aq = tid & 3;        // A: row ar, k-chunk aq (8 floats)

  float4 av0, av1;
  uint4  bu0, bu1;

  auto load_g = [&](int s) {
    int k0 = s * 32;
    int row = row0 + ar;
    av0 = make_float4(0.f, 0.f, 0.f, 0.f);
    av1 = av0;
    if (row < NN) {
      const float* gp = X + (size_t)row * FIN + k0 + aq * 8;
      av0 = *(const float4*)gp;
      av1 = *(const float4*)(gp + 4);
    }
    const uint4* bp = W1fv + (size_t)s * 512;
    bu0 = bp[tid];
    bu1 = bp[tid + 256];
  };
  auto store_l = [&](int buf) {
    char* Ab = lds + buf * G1_BUF;
    char* Bb = Ab + G1_ABUF;
    uint4 ap;
    ap.x = pack2bf(av0.x, av0.y); ap.y = pack2bf(av0.z, av0.w);
    ap.z = pack2bf(av1.x, av1.y); ap.w = pack2bf(av1.z, av1.w);
    *(uint4*)(Ab + ar * 80 + aq * 16) = ap;
    *(uint4*)(Bb + tid * 16)        = bu0;   // linear -> conflict-free
    *(uint4*)(Bb + tid * 16 + 4096) = bu1;
  };

  f32x4 acc[8];
#pragma unroll
  for (int f = 0; f < 8; ++f) acc[f] = (f32x4){0.f, 0.f, 0.f, 0.f};

  load_g(0);
  store_l(0);

  for (int s = 0; s < G1_NSTEP; ++s) {
    if (s + 1 < G1_NSTEP) load_g(s + 1);
    __syncthreads();
    const char* Ab = lds + (s & 1) * G1_BUF;
    const char* Bb = Ab + G1_ABUF;
    bf16x8 xa = *(const bf16x8*)(Ab + (w * 16 + (lane & 15)) * 80 + (lane >> 4) * 16);
#pragma unroll
    for (int f = 0; f < 8; ++f) {
      bf16x8 bt = *(const bf16x8*)(Bb + f * 1024 + lane * 16);
      acc[f] = __builtin_amdgcn_mfma_f32_16x16x32_bf16(bt, xa, acc[f], 0, 0, 0);
    }
    if (s + 1 < G1_NSTEP) store_l((s + 1) & 1);
  }

  int orow = row0 + w * 16 + (lane & 15);
  if (orow < NN) {
    size_t base = (size_t)orow * H1F;
#pragma unroll
    for (int f = 0; f < 8; ++f) {
      int col = f * 16 + (lane >> 4) * 4;
      uint2 pk;
      pk.x = pack2bf(acc[f][0], acc[f][1]);
      pk.y = pack2bf(acc[f][2], acc[f][3]);
      *(uint2*)(outb + base + col) = pk;
    }
  }
}

// ---------------- aggregation over bf16 feature table ----------------

template<bool BIAS, bool OUTBF>
__global__ __launch_bounds__(256) void k_aggb(const unsigned* __restrict__ feat,   // [NN][64] uints
                                              const int* __restrict__ rowptr,
                                              const int* __restrict__ csr,
                                              const float* __restrict__ dinv,
                                              const float* __restrict__ bias,
                                              void* __restrict__ out) {
  int gw   = (blockIdx.x * 256 + threadIdx.x) >> 6;   // dst node
  int lane = threadIdx.x & 63;
  if (gw >= NN) return;
  int beg = rowptr[gw], end = rowptr[gw + 1];
  float di = dinv[gw];
  float ax = 0.f, ay = 0.f;

  for (int e = beg; e < end; e += 64) {
    int cnt = end - e; if (cnt > 64) cnt = 64;
    int sv = 0; float wv = 0.f;
    if (lane < cnt) { sv = csr[e + lane]; wv = dinv[sv]; }
    int j = 0;
    for (; j + 4 <= cnt; j += 4) {
      int s0 = __shfl(sv, j),     s1 = __shfl(sv, j + 1);
      int s2 = __shfl(sv, j + 2), s3 = __shfl(sv, j + 3);
      float w0 = __shfl(wv, j),     w1 = __shfl(wv, j + 1);
      float w2 = __shfl(wv, j + 2), w3 = __shfl(wv, j + 3);
      unsigned v0 = feat[(size_t)s0 * 64 + lane];
      unsigned v1 = feat[(size_t)s1 * 64 + lane];
      unsigned v2 = feat[(size_t)s2 * 64 + lane];
      unsigned v3 = feat[(size_t)s3 * 64 + lane];
      ax += w0 * bflo(v0); ay += w0 * bfhi(v0);
      ax += w1 * bflo(v1); ay += w1 * bfhi(v1);
      ax += w2 * bflo(v2); ay += w2 * bfhi(v2);
      ax += w3 * bflo(v3); ay += w3 * bfhi(v3);
    }
    for (; j < cnt; ++j) {
      int s = __shfl(sv, j);
      float w = __shfl(wv, j);
      unsigned v = feat[(size_t)s * 64 + lane];
      ax += w * bflo(v); ay += w * bfhi(v);
    }
  }
  // self loop
  unsigned vd = feat[(size_t)gw * 64 + lane];
  ax = di * (ax + di * bflo(vd));
  ay = di * (ay + di * bfhi(vd));
  if (BIAS) { ax += bias[lane * 2]; ay += bias[lane * 2 + 1]; }
  if (OUTBF) {
    ((unsigned*)out)[(size_t)gw * 64 + lane] = pack2bf(ax, ay);
  } else {
    ((float2*)out)[(size_t)gw * 64 + lane] = make_float2(ax, ay);
  }
}

// ---------------- GEMM2 (MFMA) + epilogue: z = eps*exp(g@W3+b3) + g@W2+b2 ----------------
// Single-shot staging: A tile 64x128 bf16 (272B row stride), B = whole W23f (32KB).

#define G2_ASTRIDE 272
#define G2_AOFF    (64 * G2_ASTRIDE)   // 17408
#define G2_BBYTES  32768

__global__ __launch_bounds__(256) void k_gemm2m(const unsigned short* __restrict__ Gb,
                                                const uint4* __restrict__ W23fv,
                                                const float* __restrict__ b2,
                                                const float* __restrict__ b3,
                                                const float* __restrict__ eps,
                                                float* __restrict__ z) {
  __shared__ char lds[G2_AOFF + G2_BBYTES];
  int tid  = threadIdx.x;
  int row0 = blockIdx.x * 64;
  int w    = tid >> 6;
  int lane = tid & 63;

  // stage A: thread (ar, aq) copies 64B of g row ar
  {
    int ar = tid >> 2, aq = tid & 3;
    int row = row0 + ar;
    uint4 a0 = {}, a1 = {}, a2 = {}, a3 = {};
    if (row < NN) {
      const uint4* gp = (const uint4*)(Gb + (size_t)row * H1F) + aq * 4;
      a0 = gp[0]; a1 = gp[1]; a2 = gp[2]; a3 = gp[3];
    }
    char* Ab = lds + ar * G2_ASTRIDE + aq * 64;
    *(uint4*)(Ab)      = a0;
    *(uint4*)(Ab + 16) = a1;
    *(uint4*)(Ab + 32) = a2;
    *(uint4*)(Ab + 48) = a3;
  }
  // stage B: 2048 chunks, linear copy
  {
    uint4* Bb = (uint4*)(lds + G2_AOFF);
#pragma unroll
    for (int j = 0; j < 8; ++j) Bb[tid + j * 256] = W23fv[tid + j * 256];
  }
  __syncthreads();

  f32x4 acc[8];
#pragma unroll
  for (int f = 0; f < 8; ++f) acc[f] = (f32x4){0.f, 0.f, 0.f, 0.f};

#pragma unroll
  for (int s = 0; s < 4; ++s) {
    bf16x8 xa = *(const bf16x8*)(lds + (w * 16 + (lane & 15)) * G2_ASTRIDE + s * 64 + (lane >> 4) * 16);
#pragma unroll
    for (int f = 0; f < 8; ++f) {
      bf16x8 bt = *(const bf16x8*)(lds + G2_AOFF + ((s * 512 + f * 64 + lane) << 4));
      acc[f] = __builtin_amdgcn_mfma_f32_16x16x32_bf16(bt, xa, acc[f], 0, 0, 0);
    }
  }

  int orow = row0 + w * 16 + (lane & 15);
  if (orow < NN) {
    int q = lane >> 4;
    size_t base = (size_t)orow * 64;
#pragma unroll
    for (int f = 0; f < 4; ++f) {
      int c = f * 16 + q * 4;
      float4 ev = *(const float4*)&eps[base + c];
      float4 zo;
      zo.x = ev.x * __expf(acc[f + 4][0] + b3[c + 0]) + acc[f][0] + b2[c + 0];
      zo.y = ev.y * __expf(acc[f + 4][1] + b3[c + 1]) + acc[f][1] + b2[c + 1];
      zo.z = ev.z * __expf(acc[f + 4][2] + b3[c + 2]) + acc[f][2] + b2[c + 2];
      zo.w = ev.w * __expf(acc[f + 4][3] + b3[c + 3]) + acc[f][3] + b2[c + 3];
      *(float4*)&z[base + c] = zo;
    }
  }
}

// ---------------- launch ----------------

extern "C" void kernel_launch(void* const* d_in, const int* in_sizes, int n_in,
                              void* d_out, int out_size, void* d_ws, size_t ws_size,
                              hipStream_t stream) {
  const float* x   = (const float*)d_in[0];
  const int*   ei  = (const int*)  d_in[1];
  const float* W1  = (const float*)d_in[2];
  const float* b1  = (const float*)d_in[3];
  const float* W2  = (const float*)d_in[4];
  const float* b2  = (const float*)d_in[5];
  const float* W3  = (const float*)d_in[6];
  const float* b3  = (const float*)d_in[7];
  const float* eps = (const float*)d_in[8];
  float* z = (float*)d_out;

  char* ws = (char*)d_ws;
  size_t o = 0;
  auto alloc = [&](size_t bytes) -> void* {
    void* p = ws + o;
    o = (o + bytes + 255) & ~(size_t)255;
    return p;
  };
  int*   gh     = (int*)  alloc((size_t)NBUK * NBIN * 4);
  int*   btot   = (int*)  alloc((size_t)NBUK * 4);
  int*   bbase  = (int*)  alloc((size_t)(NBUK + 1) * 4);
  int*   rowptr = (int*)  alloc((size_t)(NN + 1) * 4);
  float* dinv   = (float*)alloc((size_t)NN * 4);
  int*   csr    = (int*)  alloc((size_t)NE * 4);
  unsigned* tmp = (unsigned*)alloc((size_t)NE * 4);
  unsigned short* W1f  = (unsigned short*)alloc((size_t)16 * 8 * 64 * 8 * 2);  // 128KB
  unsigned short* W23f = (unsigned short*)alloc((size_t)4 * 8 * 64 * 8 * 2);   // 32KB
  unsigned short* hw1b = (unsigned short*)alloc((size_t)NN * H1F * 2);   // bf16 x@W1
  unsigned short* h1b  = (unsigned short*)alloc((size_t)NN * H1F * 2);   // bf16 h1
  unsigned short* gb   = (unsigned short*)alloc((size_t)NN * H1F * 2);   // bf16 Agg(h1)

  k_binhist<<<NBIN, 256, 0, stream>>>(ei, gh);
  k_rowscan<<<NBUK, 64, 0, stream>>>(gh, btot);
  k_bscan  <<<1, 512, 0, stream>>>(btot, bbase);
  k_binscat<<<NBIN, 256, 0, stream>>>(ei, gh, bbase, tmp);
  k_fill2x <<<NBUK, 256, 0, stream>>>(tmp, bbase, rowptr, dinv, csr);
  k_cvtw1f <<<32, 256, 0, stream>>>(W1, W1f);
  k_cvtw23f<<<8, 256, 0, stream>>>(W2, W3, W23f);

  k_gemm1m <<<(NN + 63) / 64, 256, 0, stream>>>(x, (const uint4*)W1f, hw1b);
  k_aggb<true,  true><<<(NN + 3) / 4, 256, 0, stream>>>((const unsigned*)hw1b, rowptr, csr, dinv, b1, (void*)h1b);
  k_aggb<false, true><<<(NN + 3) / 4, 256, 0, stream>>>((const unsigned*)h1b,  rowptr, csr, dinv, nullptr, (void*)gb);
  k_gemm2m <<<(NN + 63) / 64, 256, 0, stream>>>(gb, (const uint4*)W23f, b2, b3, eps, z);
}

// Round 8
// 187.657 us; speedup vs baseline: 1.8752x; 1.0021x over previous
//
#include <hip/hip_runtime.h>
#include <math.h>

#define NN   50000
#define NE   1600000
#define FIN  512
#define H1F  128
#define NBUK  391    // ceil(NN/128)  — dst-bucket = 128 consecutive nodes
#define BIN_EPB 4096 // edges per binning block (16 per thread)
#define NBIN  391    // ceil(NE/BIN_EPB)

typedef __attribute__((ext_vector_type(8))) short bf16x8;
typedef __attribute__((ext_vector_type(4))) float f32x4;

// ---------------- bf16 helpers ----------------
__device__ __forceinline__ float bflo(unsigned v) { return __uint_as_float(v << 16); }
__device__ __forceinline__ float bfhi(unsigned v) { return __uint_as_float(v & 0xffff0000u); }
__device__ __forceinline__ unsigned short f2bf(float f) {
  unsigned u = __float_as_uint(f);
  u += 0x7fffu + ((u >> 16) & 1u);   // round-to-nearest-even
  return (unsigned short)(u >> 16);
}
__device__ __forceinline__ unsigned pack2bf(float a, float b) {
  return (unsigned)f2bf(a) | ((unsigned)f2bf(b) << 16);
}

// ---------------- CSR build: radix partition, ZERO global atomics ----------------

__global__ __launch_bounds__(256) void k_binhist(const int* __restrict__ ei,
                                                 int* __restrict__ gh) {
  __shared__ int hist[NBUK];
  int t  = threadIdx.x;
  int e0 = blockIdx.x * BIN_EPB;
  for (int b = t; b < NBUK; b += 256) hist[b] = 0;
  __syncthreads();
#pragma unroll
  for (int j = 0; j < 16; ++j) {
    int e = e0 + j * 256 + t;
    if (e < NE) atomicAdd(&hist[ei[NE + e] >> 7], 1);
  }
  __syncthreads();
  for (int b = t; b < NBUK; b += 256) gh[(size_t)b * NBIN + blockIdx.x] = hist[b];
}

__global__ __launch_bounds__(64) void k_rowscan(int* __restrict__ gh,
                                                int* __restrict__ btot) {
  int row  = blockIdx.x;
  int lane = threadIdx.x;
  int* g = gh + (size_t)row * NBIN;
  int carry = 0;
  for (int c = 0; c < (NBIN + 63) / 64; ++c) {
    int idx = c * 64 + lane;
    int v = (idx < NBIN) ? g[idx] : 0;
    int incl = v;
#pragma unroll
    for (int off = 1; off < 64; off <<= 1) {
      int u = __shfl_up(incl, off, 64);
      if (lane >= off) incl += u;
    }
    if (idx < NBIN) g[idx] = carry + (incl - v);
    carry += __shfl(incl, 63, 64);
  }
  if (lane == 0) btot[row] = carry;
}

__global__ __launch_bounds__(512) void k_bscan(const int* __restrict__ btot,
                                               int* __restrict__ bbase) {
  __shared__ int ts[512];
  int t = threadIdx.x;
  int v = (t < NBUK) ? btot[t] : 0;
  ts[t] = v;
  __syncthreads();
  for (int off = 1; off < 512; off <<= 1) {
    int val = ts[t];
    int add = (t >= off) ? ts[t - off] : 0;
    __syncthreads();
    ts[t] = val + add;
    __syncthreads();
  }
  if (t < NBUK) bbase[t] = ts[t] - v;
  if (t == NBUK - 1) bbase[NBUK] = ts[t];   // == NE
}

__global__ __launch_bounds__(256) void k_binscat(const int* __restrict__ ei,
                                                 const int* __restrict__ gh,
                                                 const int* __restrict__ bbase,
                                                 unsigned* __restrict__ tmp) {
  __shared__ int hist[NBUK];
  __shared__ int sbase[NBUK];
  int t  = threadIdx.x;
  int e0 = blockIdx.x * BIN_EPB;
  for (int b = t; b < NBUK; b += 256) hist[b] = 0;
  __syncthreads();

  unsigned short d16[16];
  unsigned short p16[16];
#pragma unroll
  for (int j = 0; j < 16; ++j) {
    int e = e0 + j * 256 + t;
    d16[j] = 0xFFFFu;
    if (e < NE) {
      int d = ei[NE + e];
      d16[j] = (unsigned short)d;
      p16[j] = (unsigned short)atomicAdd(&hist[d >> 7], 1);
    }
  }
  __syncthreads();
  for (int b = t; b < NBUK; b += 256)
    sbase[b] = bbase[b] + gh[(size_t)b * NBIN + blockIdx.x];
  __syncthreads();
#pragma unroll
  for (int j = 0; j < 16; ++j) {
    int e = e0 + j * 256 + t;
    if (e < NE) {
      int s = ei[e];
      int d = (int)d16[j];
      tmp[sbase[d >> 7] + (int)p16[j]] = ((unsigned)s << 16) | (unsigned)d;
    }
  }
}

__global__ __launch_bounds__(256) void k_fill2x(const unsigned* __restrict__ tmp,
                                                const int* __restrict__ bbase,
                                                int* __restrict__ rowptr,
                                                float* __restrict__ dinv,
                                                int* __restrict__ csr) {
  __shared__ int cnt[128];
  __shared__ int lofs[128];
  __shared__ int cur[128];
  __shared__ int ts[256];
  int b  = blockIdx.x;
  int t  = threadIdx.x;
  int n0 = b << 7;
  int beg = bbase[b];
  int end = bbase[b + 1];
  if (t < 128) { cnt[t] = 0; cur[t] = 0; }
  __syncthreads();
  for (int i = beg + t; i < end; i += 256)
    atomicAdd(&cnt[tmp[i] & 127u], 1);   // d - n0 == d & 127
  __syncthreads();
  int v = (t < 128) ? cnt[t] : 0;
  ts[t] = v;
  __syncthreads();
  for (int off = 1; off < 128; off <<= 1) {
    int val = ts[t];
    int add = (t >= off) ? ts[t - off] : 0;
    __syncthreads();
    ts[t] = val + add;
    __syncthreads();
  }
  if (t < 128) {
    int excl = ts[t] - v;
    lofs[t] = beg + excl;
    int n = n0 + t;
    if (n < NN) {
      rowptr[n] = beg + excl;
      dinv[n]   = rsqrtf((float)(v + 1));   // self-loop included
    }
  }
  if (b == NBUK - 1 && t == 0) rowptr[NN] = end;
  __syncthreads();
  for (int i = beg + t; i < end; i += 256) {
    unsigned pk = tmp[i];
    int dl = (int)(pk & 127u);
    int s  = (int)(pk >> 16);
    int p  = atomicAdd(&cur[dl], 1);
    csr[lofs[dl] + p] = s;
  }
}

// ---------------- weight repack: fragment-order bf16 ----------------

__global__ __launch_bounds__(256) void k_cvtw1f(const float* __restrict__ W,
                                                unsigned short* __restrict__ W1f) {
  int i = blockIdx.x * 256 + threadIdx.x;   // 8192 chunks
  if (i >= 16 * 8 * 64) return;
  int s = i >> 9, rem = i & 511, f = rem >> 6, lane = rem & 63;
  int row = f * 16 + (lane & 15);
  int kb  = s * 32 + (lane >> 4) * 8;
  unsigned short c8[8];
#pragma unroll
  for (int j = 0; j < 8; ++j) c8[j] = f2bf(W[(size_t)(kb + j) * H1F + row]);
  *(uint4*)&W1f[(size_t)i * 8] = *(uint4*)c8;
}

__global__ __launch_bounds__(256) void k_cvtw23f(const float* __restrict__ W2,
                                                 const float* __restrict__ W3,
                                                 unsigned short* __restrict__ Wf) {
  int i = blockIdx.x * 256 + threadIdx.x;   // 2048 chunks
  if (i >= 4 * 8 * 64) return;
  int s = i >> 9, rem = i & 511, f = rem >> 6, lane = rem & 63;
  int row = f * 16 + (lane & 15);
  int kb  = s * 32 + (lane >> 4) * 8;
  const float* Wsrc = (row < 64) ? W2 : W3;
  int c = row & 63;
  unsigned short c8[8];
#pragma unroll
  for (int j = 0; j < 8; ++j) c8[j] = f2bf(Wsrc[(size_t)(kb + j) * 64 + c]);
  *(uint4*)&Wf[(size_t)i * 8] = *(uint4*)c8;
}

// ---------------- GEMM1 (MFMA): hw1 = bf16(x @ W1) ----------------

#define G1_ABUF 5120                  // 64 rows * 80B
#define G1_BBUF 8192                  // 512 chunks * 16B
#define G1_BUF  (G1_ABUF + G1_BBUF)
#define G1_NSTEP 16

__global__ __launch_bounds__(256) void k_gemm1m(const float* __restrict__ X,
                                                const uint4* __restrict__ W1fv,
                                                unsigned short* __restrict__ outb) {
  __shared__ char lds[2 * G1_BUF];
  int tid  = threadIdx.x;
  int row0 = blockIdx.x * 64;
  int w    = tid >> 6;
  int lane = tid & 63;

  int ar = tid >> 2, aq = tid & 3;        // A: row ar, k-chunk aq (8 floats)

  float4 av0, av1;
  uint4  bu0, bu1;

  auto load_g = [&](int s) {
    int k0 = s * 32;
    int row = row0 + ar;
    av0 = make_float4(0.f, 0.f, 0.f, 0.f);
    av1 = av0;
    if (row < NN) {
      const float* gp = X + (size_t)row * FIN + k0 + aq * 8;
      av0 = *(const float4*)gp;
      av1 = *(const float4*)(gp + 4);
    }
    const uint4* bp = W1fv + (size_t)s * 512;
    bu0 = bp[tid];
    bu1 = bp[tid + 256];
  };
  auto store_l = [&](int buf) {
    char* Ab = lds + buf * G1_BUF;
    char* Bb = Ab + G1_ABUF;
    uint4 ap;
    ap.x = pack2bf(av0.x, av0.y); ap.y = pack2bf(av0.z, av0.w);
    ap.z = pack2bf(av1.x, av1.y); ap.w = pack2bf(av1.z, av1.w);
    *(uint4*)(Ab + ar * 80 + aq * 16) = ap;
    *(uint4*)(Bb + tid * 16)        = bu0;   // linear -> conflict-free
    *(uint4*)(Bb + tid * 16 + 4096) = bu1;
  };

  f32x4 acc[8];
#pragma unroll
  for (int f = 0; f < 8; ++f) acc[f] = (f32x4){0.f, 0.f, 0.f, 0.f};

  load_g(0);
  store_l(0);

  for (int s = 0; s < G1_NSTEP; ++s) {
    if (s + 1 < G1_NSTEP) load_g(s + 1);
    __syncthreads();
    const char* Ab = lds + (s & 1) * G1_BUF;
    const char* Bb = Ab + G1_ABUF;
    bf16x8 xa = *(const bf16x8*)(Ab + (w * 16 + (lane & 15)) * 80 + (lane >> 4) * 16);
#pragma unroll
    for (int f = 0; f < 8; ++f) {
      bf16x8 bt = *(const bf16x8*)(Bb + f * 1024 + lane * 16);
      acc[f] = __builtin_amdgcn_mfma_f32_16x16x32_bf16(bt, xa, acc[f], 0, 0, 0);
    }
    if (s + 1 < G1_NSTEP) store_l((s + 1) & 1);
  }

  int orow = row0 + w * 16 + (lane & 15);
  if (orow < NN) {
    size_t base = (size_t)orow * H1F;
#pragma unroll
    for (int f = 0; f < 8; ++f) {
      int col = f * 16 + (lane >> 4) * 4;
      uint2 pk;
      pk.x = pack2bf(acc[f][0], acc[f][1]);
      pk.y = pack2bf(acc[f][2], acc[f][3]);
      *(uint2*)(outb + base + col) = pk;
    }
  }
}

// ---------------- aggregation over bf16 feature table ----------------
// 32-lane groups: each wave handles 2 dst nodes, each group gathers a full
// 256B row (uint2/lane). 2 independent edge chains per wave + 4-deep unroll
// = 8 gathers in flight (vs 4 before) — attacks gather latency.

template<bool BIAS, bool OUTBF>
__global__ __launch_bounds__(256) void k_aggb(const unsigned* __restrict__ feat,   // [NN][64] uints
                                              const int* __restrict__ rowptr,
                                              const int* __restrict__ csr,
                                              const float* __restrict__ dinv,
                                              const float* __restrict__ bias,
                                              void* __restrict__ out) {
  int gw   = (blockIdx.x * 256 + threadIdx.x) >> 5;   // dst node (group of 32)
  int lane = threadIdx.x & 31;
  if (gw >= NN) return;
  int beg = rowptr[gw], end = rowptr[gw + 1];
  float di = dinv[gw];
  float ax = 0.f, ay = 0.f, az = 0.f, aw = 0.f;

  for (int e = beg; e < end; e += 32) {
    int cnt = end - e; if (cnt > 32) cnt = 32;
    int sv = 0; float wv = 0.f;
    if (lane < cnt) { sv = csr[e + lane]; wv = dinv[sv]; }
    int j = 0;
    for (; j + 4 <= cnt; j += 4) {
      int s0 = __shfl(sv, j, 32),     s1 = __shfl(sv, j + 1, 32);
      int s2 = __shfl(sv, j + 2, 32), s3 = __shfl(sv, j + 3, 32);
      float w0 = __shfl(wv, j, 32),     w1 = __shfl(wv, j + 1, 32);
      float w2 = __shfl(wv, j + 2, 32), w3 = __shfl(wv, j + 3, 32);
      uint2 v0 = *(const uint2*)&feat[(size_t)s0 * 64 + lane * 2];
      uint2 v1 = *(const uint2*)&feat[(size_t)s1 * 64 + lane * 2];
      uint2 v2 = *(const uint2*)&feat[(size_t)s2 * 64 + lane * 2];
      uint2 v3 = *(const uint2*)&feat[(size_t)s3 * 64 + lane * 2];
      ax += w0 * bflo(v0.x); ay += w0 * bfhi(v0.x); az += w0 * bflo(v0.y); aw += w0 * bfhi(v0.y);
      ax += w1 * bflo(v1.x); ay += w1 * bfhi(v1.x); az += w1 * bflo(v1.y); aw += w1 * bfhi(v1.y);
      ax += w2 * bflo(v2.x); ay += w2 * bfhi(v2.x); az += w2 * bflo(v2.y); aw += w2 * bfhi(v2.y);
      ax += w3 * bflo(v3.x); ay += w3 * bfhi(v3.x); az += w3 * bflo(v3.y); aw += w3 * bfhi(v3.y);
    }
    for (; j < cnt; ++j) {
      int s = __shfl(sv, j, 32);
      float w = __shfl(wv, j, 32);
      uint2 v = *(const uint2*)&feat[(size_t)s * 64 + lane * 2];
      ax += w * bflo(v.x); ay += w * bfhi(v.x); az += w * bflo(v.y); aw += w * bfhi(v.y);
    }
  }
  // self loop
  uint2 vd = *(const uint2*)&feat[(size_t)gw * 64 + lane * 2];
  ax = di * (ax + di * bflo(vd.x));
  ay = di * (ay + di * bfhi(vd.x));
  az = di * (az + di * bflo(vd.y));
  aw = di * (aw + di * bfhi(vd.y));
  if (BIAS) {
    float4 bb = *(const float4*)&bias[lane * 4];
    ax += bb.x; ay += bb.y; az += bb.z; aw += bb.w;
  }
  if (OUTBF) {
    uint2 pk; pk.x = pack2bf(ax, ay); pk.y = pack2bf(az, aw);
    *(uint2*)&((unsigned*)out)[(size_t)gw * 64 + lane * 2] = pk;
  } else {
    *(float4*)&((float*)out)[(size_t)gw * H1F + lane * 4] = make_float4(ax, ay, az, aw);
  }
}

// ---------------- GEMM2 (MFMA) + epilogue: z = eps*exp(g@W3+b3) + g@W2+b2 ----------------

#define G2_ASTRIDE 272
#define G2_AOFF    (64 * G2_ASTRIDE)   // 17408
#define G2_BBYTES  32768

__global__ __launch_bounds__(256) void k_gemm2m(const unsigned short* __restrict__ Gb,
                                                const uint4* __restrict__ W23fv,
                                                const float* __restrict__ b2,
                                                const float* __restrict__ b3,
                                                const float* __restrict__ eps,
                                                float* __restrict__ z) {
  __shared__ char lds[G2_AOFF + G2_BBYTES];
  int tid  = threadIdx.x;
  int row0 = blockIdx.x * 64;
  int w    = tid >> 6;
  int lane = tid & 63;

  {
    int ar = tid >> 2, aq = tid & 3;
    int row = row0 + ar;
    uint4 a0 = {}, a1 = {}, a2 = {}, a3 = {};
    if (row < NN) {
      const uint4* gp = (const uint4*)(Gb + (size_t)row * H1F) + aq * 4;
      a0 = gp[0]; a1 = gp[1]; a2 = gp[2]; a3 = gp[3];
    }
    char* Ab = lds + ar * G2_ASTRIDE + aq * 64;
    *(uint4*)(Ab)      = a0;
    *(uint4*)(Ab + 16) = a1;
    *(uint4*)(Ab + 32) = a2;
    *(uint4*)(Ab + 48) = a3;
  }
  {
    uint4* Bb = (uint4*)(lds + G2_AOFF);
#pragma unroll
    for (int j = 0; j < 8; ++j) Bb[tid + j * 256] = W23fv[tid + j * 256];
  }
  __syncthreads();

  f32x4 acc[8];
#pragma unroll
  for (int f = 0; f < 8; ++f) acc[f] = (f32x4){0.f, 0.f, 0.f, 0.f};

#pragma unroll
  for (int s = 0; s < 4; ++s) {
    bf16x8 xa = *(const bf16x8*)(lds + (w * 16 + (lane & 15)) * G2_ASTRIDE + s * 64 + (lane >> 4) * 16);
#pragma unroll
    for (int f = 0; f < 8; ++f) {
      bf16x8 bt = *(const bf16x8*)(lds + G2_AOFF + ((s * 512 + f * 64 + lane) << 4));
      acc[f] = __builtin_amdgcn_mfma_f32_16x16x32_bf16(bt, xa, acc[f], 0, 0, 0);
    }
  }

  int orow = row0 + w * 16 + (lane & 15);
  if (orow < NN) {
    int q = lane >> 4;
    size_t base = (size_t)orow * 64;
#pragma unroll
    for (int f = 0; f < 4; ++f) {
      int c = f * 16 + q * 4;
      float4 ev = *(const float4*)&eps[base + c];
      float4 zo;
      zo.x = ev.x * __expf(acc[f + 4][0] + b3[c + 0]) + acc[f][0] + b2[c + 0];
      zo.y = ev.y * __expf(acc[f + 4][1] + b3[c + 1]) + acc[f][1] + b2[c + 1];
      zo.z = ev.z * __expf(acc[f + 4][2] + b3[c + 2]) + acc[f][2] + b2[c + 2];
      zo.w = ev.w * __expf(acc[f + 4][3] + b3[c + 3]) + acc[f][3] + b2[c + 3];
      *(float4*)&z[base + c] = zo;
    }
  }
}

// ---------------- launch ----------------

extern "C" void kernel_launch(void* const* d_in, const int* in_sizes, int n_in,
                              void* d_out, int out_size, void* d_ws, size_t ws_size,
                              hipStream_t stream) {
  const float* x   = (const float*)d_in[0];
  const int*   ei  = (const int*)  d_in[1];
  const float* W1  = (const float*)d_in[2];
  const float* b1  = (const float*)d_in[3];
  const float* W2  = (const float*)d_in[4];
  const float* b2  = (const float*)d_in[5];
  const float* W3  = (const float*)d_in[6];
  const float* b3  = (const float*)d_in[7];
  const float* eps = (const float*)d_in[8];
  float* z = (float*)d_out;

  char* ws = (char*)d_ws;
  size_t o = 0;
  auto alloc = [&](size_t bytes) -> void* {
    void* p = ws + o;
    o = (o + bytes + 255) & ~(size_t)255;
    return p;
  };
  int*   gh     = (int*)  alloc((size_t)NBUK * NBIN * 4);
  int*   btot   = (int*)  alloc((size_t)NBUK * 4);
  int*   bbase  = (int*)  alloc((size_t)(NBUK + 1) * 4);
  int*   rowptr = (int*)  alloc((size_t)(NN + 1) * 4);
  float* dinv   = (float*)alloc((size_t)NN * 4);
  int*   csr    = (int*)  alloc((size_t)NE * 4);
  unsigned* tmp = (unsigned*)alloc((size_t)NE * 4);
  unsigned short* W1f  = (unsigned short*)alloc((size_t)16 * 8 * 64 * 8 * 2);  // 128KB
  unsigned short* W23f = (unsigned short*)alloc((size_t)4 * 8 * 64 * 8 * 2);   // 32KB
  unsigned short* hw1b = (unsigned short*)alloc((size_t)NN * H1F * 2);   // bf16 x@W1
  unsigned short* h1b  = (unsigned short*)alloc((size_t)NN * H1F * 2);   // bf16 h1
  unsigned short* gb   = (unsigned short*)alloc((size_t)NN * H1F * 2);   // bf16 Agg(h1)

  k_binhist<<<NBIN, 256, 0, stream>>>(ei, gh);
  k_rowscan<<<NBUK, 64, 0, stream>>>(gh, btot);
  k_bscan  <<<1, 512, 0, stream>>>(btot, bbase);
  k_binscat<<<NBIN, 256, 0, stream>>>(ei, gh, bbase, tmp);
  k_fill2x <<<NBUK, 256, 0, stream>>>(tmp, bbase, rowptr, dinv, csr);
  k_cvtw1f <<<32, 256, 0, stream>>>(W1, W1f);
  k_cvtw23f<<<8, 256, 0, stream>>>(W2, W3, W23f);

  k_gemm1m <<<(NN + 63) / 64, 256, 0, stream>>>(x, (const uint4*)W1f, hw1b);
  k_aggb<true,  true><<<(NN * 32 + 255) / 256, 256, 0, stream>>>((const unsigned*)hw1b, rowptr, csr, dinv, b1, (void*)h1b);
  k_aggb<false, true><<<(NN * 32 + 255) / 256, 256, 0, stream>>>((const unsigned*)h1b,  rowptr, csr, dinv, nullptr, (void*)gb);
  k_gemm2m <<<(NN + 63) / 64, 256, 0, stream>>>(gb, (const uint4*)W23f, b2, b3, eps, z);
}